// Round 28
// baseline (2791.532 us; speedup 1.0000x reference)
//
#include <hip/hip_runtime.h>
#include <hip/hip_bf16.h>
#include <math.h>

#define D_P 128
#define D_T 256
#define D_F 384
#define DIM 768
#define NUM_TIMES 601
#define NUM_F0 360
#define NHEAD 12
#define HD 64
#define NLAYERS 6
#define DFF 2048
#define CTX 1024
#define SEQ 1088
#define BATCH 8
#define ROWS (BATCH*SEQ)
#define TDIM3 (3*DIM)
#define PREDROWS 512

typedef unsigned short ushort_t;
typedef __attribute__((ext_vector_type(8))) short bfrag;
typedef __attribute__((ext_vector_type(4))) float f32x4;

// Required template symbol; also the guard-path fill kernel.
__global__ void SequenceModel_30425548325019_kernel(unsigned short* out, int n, unsigned short v) {
  int i = blockIdx.x * 256 + threadIdx.x;
  if (i < n) out[i] = v;
}

__device__ inline short f2bf(float f) {
  unsigned u = __float_as_uint(f);
  unsigned r = (u + 0x7FFFu + ((u >> 16) & 1u)) >> 16;  // RNE
  return (short)r;
}

__device__ inline float bflo(unsigned u) { return __uint_as_float(u << 16); }
__device__ inline float bfhi(unsigned u) { return __uint_as_float(u & 0xFFFF0000u); }
__device__ inline unsigned packbf(float a, float b) {
  return ((unsigned)(ushort_t)f2bf(a)) | (((unsigned)(ushort_t)f2bf(b)) << 16);
}

__device__ inline void gload16(const void* g, void* l) {
  __builtin_amdgcn_global_load_lds(
      (const __attribute__((address_space(1))) unsigned*)g,
      (__attribute__((address_space(3))) unsigned*)l, 16, 0, 0);
}

// ---------------- fp32 -> bf16 bulk convert ----------------
__global__ __launch_bounds__(256) void cvt_bf16(const float* __restrict__ src,
                                                ushort_t* __restrict__ dst, int n) {
  int i = (blockIdx.x * 256 + threadIdx.x) * 4;
  if (i >= n) return;
  float4 v = *(const float4*)(src + i);
  dst[i + 0] = (ushort_t)f2bf(v.x);
  dst[i + 1] = (ushort_t)f2bf(v.y);
  dst[i + 2] = (ushort_t)f2bf(v.z);
  dst[i + 3] = (ushort_t)f2bf(v.w);
}

// ---------------- embedding: writes bf16 xb only ----------------
__global__ __launch_bounds__(256) void embed_kernel(
    const int* __restrict__ cp, const float* __restrict__ ct,
    const int* __restrict__ cf, const float* __restrict__ part,
    const float* __restrict__ f0t, const float* __restrict__ pad,
    ushort_t* __restrict__ xb) {
  int idx = blockIdx.x * 256 + threadIdx.x;
  if (idx >= ROWS * DIM) return;
  int d = idx % DIM;
  int row = idx / DIM;
  int b = row / SEQ, s = row - b * SEQ;
  float v;
  if (s >= CTX) {
    v = pad[d];
  } else if (d < D_P) {
    v = part[cp[b * CTX + s] * D_P + d];
  } else if (d < D_P + D_T) {
    int j = d - D_P;
    int i2 = j >> 1;
    float wk = powf(10000.f, -(float)i2 / (float)D_T) * ((float)D_T / (float)NUM_TIMES);
    float ang = ct[b * CTX + s] * wk;
    v = (j & 1) ? cosf(ang) : sinf(ang);
  } else {
    v = f0t[cf[b * CTX + s] * D_F + (d - D_P - D_T)];
  }
  xb[idx] = (ushort_t)f2bf(v);
}

// ---------------- bf16 MFMA NT GEMM, double-buffered LDS pipeline ----------
// mode 0: Cb row-major [M][N]. mode 1: QKV-split -> [idx][B][H][S][64], Q scaled.
#define BM 128
#define BN 128
#define BK 32
#define QSCALE 0.1803368801f  // 0.125 * log2(e)

__global__ __launch_bounds__(256) void gemm_bb(
    const ushort_t* __restrict__ A, const ushort_t* __restrict__ B,
    const float* __restrict__ bias,
    ushort_t* __restrict__ Cb, int M, int N, int K, int relu, int mode) {
  __shared__ short As[2][4 * BM * 8];
  __shared__ short Bs[2][4 * BN * 8];
  const int tid = threadIdx.x;
  const int wave = tid >> 6, lane = tid & 63;
  const int wr = wave >> 1, wc = wave & 1;
  const int l15 = lane & 15, l4 = lane >> 4;
  const int m0 = blockIdx.y * BM, n0 = blockIdx.x * BN;
  f32x4 acc[4][4] = {};

  const int u0row = (wave * 64 + lane) & 127, u0kg = (wave * 64 + lane) >> 7;
  const int u1row = (256 + wave * 64 + lane) & 127, u1kg = (256 + wave * 64 + lane) >> 7;
  const ushort_t* Ap0 = A + (size_t)(m0 + u0row) * K + u0kg * 8;
  const ushort_t* Bp0 = B + (size_t)(n0 + u0row) * K + u0kg * 8;
  const ushort_t* Ap1 = A + (size_t)(m0 + u1row) * K + u1kg * 8;
  const ushort_t* Bp1 = B + (size_t)(n0 + u1row) * K + u1kg * 8;
  const int ldsoff0 = (wave * 64) * 8;
  const int ldsoff1 = (256 + wave * 64) * 8;

  gload16(Ap0, &As[0][ldsoff0]);
  gload16(Bp0, &Bs[0][ldsoff0]);
  gload16(Ap1, &As[0][ldsoff1]);
  gload16(Bp1, &Bs[0][ldsoff1]);
  __syncthreads();

  int cur = 0;
  for (int k0 = 0; k0 < K; k0 += BK) {
    if (k0 + BK < K) {
      gload16(Ap0 + k0 + BK, &As[cur ^ 1][ldsoff0]);
      gload16(Bp0 + k0 + BK, &Bs[cur ^ 1][ldsoff0]);
      gload16(Ap1 + k0 + BK, &As[cur ^ 1][ldsoff1]);
      gload16(Bp1 + k0 + BK, &Bs[cur ^ 1][ldsoff1]);
    }
    bfrag a[4], b[4];
    #pragma unroll
    for (int f = 0; f < 4; ++f) {
      a[f] = *(const bfrag*)&As[cur][(l4 * BM + wr * 64 + f * 16 + l15) * 8];
      b[f] = *(const bfrag*)&Bs[cur][(l4 * BN + wc * 64 + f * 16 + l15) * 8];
    }
    __builtin_amdgcn_s_setprio(1);
    #pragma unroll
    for (int i = 0; i < 4; ++i)
      #pragma unroll
      for (int j = 0; j < 4; ++j)
        acc[i][j] = __builtin_amdgcn_mfma_f32_16x16x32_bf16(a[i], b[j], acc[i][j], 0, 0, 0);
    __builtin_amdgcn_s_setprio(0);
    __syncthreads();
    cur ^= 1;
  }
  #pragma unroll
  for (int i = 0; i < 4; ++i) {
    int mbase = m0 + wr * 64 + i * 16 + l4 * 4;
    #pragma unroll
    for (int j = 0; j < 4; ++j) {
      int n = n0 + wc * 64 + j * 16 + l15;
      float bv = bias[n];
      if (mode == 1) {
        int idx = n / DIM;           // 0=Q 1=K 2=V
        int hh = (n - idx * DIM) >> 6;
        int d = n & 63;
        #pragma unroll
        for (int r = 0; r < 4; ++r) {
          int m = mbase + r;
          int bb_ = m / SEQ, ss = m - bb_ * SEQ;
          float v = acc[i][j][r] + bv;
          if (idx == 0) v *= QSCALE;
          size_t off = (((size_t)idx * BATCH + bb_) * NHEAD + hh) * ((size_t)SEQ * 64) +
                       (size_t)ss * 64 + d;
          Cb[off] = (ushort_t)f2bf(v);
        }
      } else {
        #pragma unroll
        for (int r = 0; r < 4; ++r) {
          int m = mbase + r;
          float v = acc[i][j][r] + bv;
          if (relu) v = fmaxf(v, 0.f);
          Cb[(size_t)m * N + n] = (ushort_t)f2bf(v);
        }
      }
    }
  }
}

// ---------------- gather pred rows (bf16) ----------------
__global__ __launch_bounds__(256) void gather_pred(const ushort_t* __restrict__ xb,
                                                   ushort_t* __restrict__ xpb) {
  int idx = blockIdx.x * 256 + threadIdx.x;
  if (idx >= PREDROWS * DIM) return;
  int r = idx / DIM, d = idx - r * DIM;
  int b = r >> 6, rr = r & 63;
  xpb[idx] = xb[(size_t)(b * SEQ + CTX + rr) * DIM + d];
}

// ---------------- head GEMM (bf16 operands, fp32 out, N-guarded stores) ------
__global__ __launch_bounds__(256) void head_mfma(
    const ushort_t* __restrict__ A, const ushort_t* __restrict__ B,
    float* __restrict__ C, int N, int K, int lda, int coloff) {
  __shared__ short As[4 * BM * 8];
  __shared__ short Bs[4 * BN * 8];
  const int tid = threadIdx.x;
  const int wave = tid >> 6, lane = tid & 63;
  const int wr = wave >> 1, wc = wave & 1;
  const int l15 = lane & 15, l4 = lane >> 4;
  const int m0 = blockIdx.y * BM, n0 = blockIdx.x * BN;
  f32x4 acc[4][4] = {};

  for (int k0 = 0; k0 < K; k0 += BK) {
    __syncthreads();
    #pragma unroll
    for (int i = 0; i < 2; ++i) {
      int u = i * 256 + wave * 64 + lane;
      int row = u & 127, kg = u >> 7;
      gload16(A + (size_t)(m0 + row) * lda + coloff + k0 + kg * 8,
              &As[(i * 256 + wave * 64) * 8]);
      gload16(B + (size_t)(n0 + row) * K + k0 + kg * 8,
              &Bs[(i * 256 + wave * 64) * 8]);
    }
    __syncthreads();
    bfrag a[4], b[4];
    #pragma unroll
    for (int f = 0; f < 4; ++f) {
      a[f] = *(const bfrag*)&As[(l4 * BM + wr * 64 + f * 16 + l15) * 8];
      b[f] = *(const bfrag*)&Bs[(l4 * BN + wc * 64 + f * 16 + l15) * 8];
    }
    #pragma unroll
    for (int i = 0; i < 4; ++i)
      #pragma unroll
      for (int j = 0; j < 4; ++j)
        acc[i][j] = __builtin_amdgcn_mfma_f32_16x16x32_bf16(a[i], b[j], acc[i][j], 0, 0, 0);
  }
  #pragma unroll
  for (int i = 0; i < 4; ++i) {
    int mbase = m0 + wr * 64 + i * 16 + l4 * 4;
    #pragma unroll
    for (int j = 0; j < 4; ++j) {
      int n = n0 + wc * 64 + j * 16 + l15;
      if (n >= N) continue;
      #pragma unroll
      for (int r = 0; r < 4; ++r)
        C[(size_t)(mbase + r) * N + n] = acc[i][j][r];
    }
  }
}

// ---------------- MFMA flash attention v8: split K/V layout ------------------
// qkvS layout: [idx(3)][B][H][S][64] bf16 (K/V rows contiguous, 128B stride).
// In-register softmax (v7); V transposed in LDS; out written [B][S][H*64].
#define QBLK 64
#define KBLK 64
__global__ __launch_bounds__(256) void attn_mfma(const ushort_t* __restrict__ qkvS,
                                                 ushort_t* __restrict__ outb) {
  const int qt = blockIdx.x, h = blockIdx.y, b = blockIdx.z;
  const int q0 = qt * QBLK;
  __shared__ char smem[8 * 64 * 9 * 2 * 2 > 64 * 65 * 4 ? 8 * 64 * 9 * 2 * 2 : 64 * 65 * 4];
  short* Vt = (short*)smem;
  short* Ps = (short*)(smem + 8 * 64 * 9 * 2);
  float* SO = (float*)smem;
  const int tid = threadIdx.x;
  const int wave = tid >> 6, lane = tid & 63;
  const int l15 = lane & 15, l4 = lane >> 4;
  const int qf = wave;

  const size_t plane = (size_t)SEQ * 64;
  const ushort_t* Qp = qkvS + ((size_t)(0 * BATCH + b) * NHEAD + h) * plane;
  const ushort_t* Kp = qkvS + ((size_t)(1 * BATCH + b) * NHEAD + h) * plane;
  const ushort_t* Vp = qkvS + ((size_t)(2 * BATCH + b) * NHEAD + h) * plane;

  bfrag aq0 = *(const bfrag*)(Qp + (size_t)(q0 + qf * 16 + l15) * 64 + l4 * 8);
  bfrag aq1 = *(const bfrag*)(Qp + (size_t)(q0 + qf * 16 + l15) * 64 + 32 + l4 * 8);

  float mrun[4], lrun[4];
  #pragma unroll
  for (int r = 0; r < 4; ++r) { mrun[r] = -1e30f; lrun[r] = 0.f; }
  f32x4 o[4] = {};
  const int nkt = (q0 < CTX) ? (q0 + QBLK) / KBLK : (CTX / KBLK);

  for (int kt = 0; kt < nkt; ++kt) {
    const int k0 = kt * KBLK;
    __syncthreads();
    // stage V transposed (rows now 128B contiguous)
    #pragma unroll
    for (int i = 0; i < 2; ++i) {
      int u = tid + 256 * i;
      int krow = u >> 3, dg = u & 7;
      bfrag vv = *(const bfrag*)(Vp + (size_t)(k0 + krow) * 64 + dg * 8);
      int kg = krow >> 3, j = krow & 7;
      #pragma unroll
      for (int e = 0; e < 8; ++e)
        Vt[(kg * 64 + dg * 8 + e) * 9 + j] = vv[e];
    }
    // QK^T: 4 S-frags in registers
    f32x4 s[4];
    #pragma unroll
    for (int jk = 0; jk < 4; ++jk) {
      const ushort_t* kr = Kp + (size_t)(k0 + jk * 16 + l15) * 64;
      bfrag bk0 = *(const bfrag*)(kr + l4 * 8);
      bfrag bk1 = *(const bfrag*)(kr + 32 + l4 * 8);
      f32x4 acc = {};
      acc = __builtin_amdgcn_mfma_f32_16x16x32_bf16(aq0, bk0, acc, 0, 0, 0);
      s[jk] = __builtin_amdgcn_mfma_f32_16x16x32_bf16(aq1, bk1, acc, 0, 0, 0);
    }
    // in-register online softmax (exp2 domain), per q-row r
    #pragma unroll
    for (int r = 0; r < 4; ++r) {
      const int qglob = q0 + qf * 16 + l4 * 4 + r;
      float pv[4];
      float tm = -1e30f;
      #pragma unroll
      for (int jk = 0; jk < 4; ++jk) {
        int kg = k0 + jk * 16 + l15;
        bool allowed = (qglob < CTX) ? (kg <= qglob) : true;
        pv[jk] = allowed ? s[jk][r] : -1e30f;
        tm = fmaxf(tm, pv[jk]);
      }
      tm = fmaxf(tm, __shfl_xor(tm, 1));
      tm = fmaxf(tm, __shfl_xor(tm, 2));
      tm = fmaxf(tm, __shfl_xor(tm, 4));
      tm = fmaxf(tm, __shfl_xor(tm, 8));
      float mn = fmaxf(mrun[r], tm);
      float alpha = exp2f(mrun[r] - mn);
      float ls = 0.f;
      #pragma unroll
      for (int jk = 0; jk < 4; ++jk) { pv[jk] = exp2f(pv[jk] - mn); ls += pv[jk]; }
      ls += __shfl_xor(ls, 1);
      ls += __shfl_xor(ls, 2);
      ls += __shfl_xor(ls, 4);
      ls += __shfl_xor(ls, 8);
      lrun[r] = lrun[r] * alpha + ls;
      mrun[r] = mn;
      #pragma unroll
      for (int df = 0; df < 4; ++df) o[df][r] *= alpha;
      const int qrow = qf * 16 + l4 * 4 + r;
      #pragma unroll
      for (int jk = 0; jk < 4; ++jk) {
        int kgi = jk * 2 + (l15 >> 3), j = l15 & 7;
        Ps[(kgi * 64 + qrow) * 9 + j] = f2bf(pv[jk]);
      }
    }
    __syncthreads();
    // PV over 64-k (2 chunks of 32)
    #pragma unroll
    for (int c = 0; c < 2; ++c) {
      bfrag pa = *(const bfrag*)&Ps[((c * 4 + l4) * 64 + qf * 16 + l15) * 9];
      #pragma unroll
      for (int df = 0; df < 4; ++df) {
        bfrag v = *(const bfrag*)&Vt[((c * 4 + l4) * 64 + df * 16 + l15) * 9];
        o[df] = __builtin_amdgcn_mfma_f32_16x16x32_bf16(pa, v, o[df], 0, 0, 0);
      }
    }
  }
  // epilogue via SO overlay, coalesced write to [B][S][H*64]
  __syncthreads();
  #pragma unroll
  for (int r = 0; r < 4; ++r) {
    float li = 1.f / lrun[r];
    #pragma unroll
    for (int df = 0; df < 4; ++df)
      SO[(qf * 16 + l4 * 4 + r) * 65 + df * 16 + l15] = o[df][r] * li;
  }
  __syncthreads();
  #pragma unroll
  for (int i = 0; i < 2; ++i) {
    int s2 = tid + 256 * i;
    int r = s2 >> 3, kg = s2 & 7;
    ushort_t* dst = outb + (size_t)(b * SEQ + q0 + r) * DIM + h * HD + kg * 8;
    const float* sp = &SO[r * 65 + kg * 8];
    bfrag t;
    #pragma unroll
    for (int e = 0; e < 8; ++e) t[e] = f2bf(sp[e]);
    *(bfrag*)dst = t;
  }
}

// ---------------- fused residual+LN, bf16-only stream: xb = LN(xb + raw) -----
__global__ __launch_bounds__(256) void ln_bb(const ushort_t* __restrict__ raw,
                                             ushort_t* __restrict__ xb,
                                             const float* __restrict__ g,
                                             const float* __restrict__ bb) {
  const int row = blockIdx.x;
  unsigned* pu = (unsigned*)(xb + (size_t)row * DIM);
  const unsigned* qu = (const unsigned*)(raw + (size_t)row * DIM);
  const float2* g2 = (const float2*)g;
  const float2* b2 = (const float2*)bb;
  const int tid = threadIdx.x;

  unsigned x0 = pu[tid], r0 = qu[tid];
  float v00 = bflo(x0) + bflo(r0);
  float v01 = bfhi(x0) + bfhi(r0);
  float v10 = 0.f, v11 = 0.f;
  if (tid < 128) {
    unsigned x1 = pu[256 + tid], r1 = qu[256 + tid];
    v10 = bflo(x1) + bflo(r1);
    v11 = bfhi(x1) + bfhi(r1);
  }
  float s1 = v00 + v01 + v10 + v11;
  float s2 = v00 * v00 + v01 * v01 + v10 * v10 + v11 * v11;
  #pragma unroll
  for (int off = 32; off >= 1; off >>= 1) {
    s1 += __shfl_down(s1, off);
    s2 += __shfl_down(s2, off);
  }
  __shared__ float r1s[4], r2s[4];
  int wid = tid >> 6;
  if ((tid & 63) == 0) { r1s[wid] = s1; r2s[wid] = s2; }
  __syncthreads();
  s1 = r1s[0] + r1s[1] + r1s[2] + r1s[3];
  s2 = r2s[0] + r2s[1] + r2s[2] + r2s[3];
  const float mu = s1 * (1.f / DIM);
  const float var = s2 * (1.f / DIM) - mu * mu;
  const float rs = rsqrtf(var + 1e-5f);
  float2 ga = g2[tid], ba = b2[tid];
  float o00 = (v00 - mu) * rs * ga.x + ba.x;
  float o01 = (v01 - mu) * rs * ga.y + ba.y;
  pu[tid] = packbf(o00, o01);
  if (tid < 128) {
    float2 gb = g2[256 + tid], bbv = b2[256 + tid];
    float o10 = (v10 - mu) * rs * gb.x + bbv.x;
    float o11 = (v11 - mu) * rs * gb.y + bbv.y;
    pu[256 + tid] = packbf(o10, o11);
  }
}

extern "C" void kernel_launch(void* const* d_in, const int* in_sizes, int n_in,
                              void* d_out, int out_size, void* d_ws, size_t ws_size,
                              hipStream_t stream) {
  const size_t N_XB   = (size_t)ROWS * DIM / 2;
  const size_t N_BUFB = (size_t)ROWS * TDIM3 / 2;
  const size_t N_CTB  = (size_t)ROWS * DIM / 2;
  const size_t N_WQ   = 10616832 / 2;
  const size_t N_WO   = 3538944 / 2;
  const size_t N_W1   = 9437184 / 2;
  const size_t N_W2   = 9437184 / 2;
  const size_t N_PT   = 8192 / 2;
  const size_t N_TT   = 153856 / 2;
  const size_t N_FT   = 138240 / 2;
  const size_t N_XPB  = (size_t)PREDROWS * DIM / 2;
  size_t need = (N_XB + N_BUFB + N_CTB + N_WQ + N_WO + N_W1 + N_W2 +
                 N_PT + N_TT + N_FT + N_XPB) * sizeof(float);
  if (ws_size < need) {
    SequenceModel_30425548325019_kernel<<<(out_size + 255) / 256, 256, 0, stream>>>(
        (unsigned short*)d_out, out_size, (unsigned short)0x4280);
    return;
  }

  const int*   cp    = (const int*)d_in[0];
  const float* ct    = (const float*)d_in[1];
  const int*   cf    = (const int*)d_in[2];
  const float* part  = (const float*)d_in[3];
  const float* timet = (const float*)d_in[4];
  const float* f0t   = (const float*)d_in[5];
  const float* pad   = (const float*)d_in[6];
  const float* Wqkv  = (const float*)d_in[7];
  const float* bqkv  = (const float*)d_in[8];
  const float* Wo    = (const float*)d_in[9];
  const float* bo    = (const float*)d_in[10];
  const float* ln1g  = (const float*)d_in[11];
  const float* ln1b  = (const float*)d_in[12];
  const float* W1    = (const float*)d_in[13];
  const float* b1    = (const float*)d_in[14];
  const float* W2    = (const float*)d_in[15];
  const float* b2    = (const float*)d_in[16];
  const float* ln2g  = (const float*)d_in[17];
  const float* ln2b  = (const float*)d_in[18];

  float* base = (float*)d_ws;
  ushort_t* xb     = (ushort_t*)base;      base += N_XB;
  ushort_t* bufb   = (ushort_t*)base;      base += N_BUFB;   // QKV split planes
  ushort_t* ctxbb  = (ushort_t*)base;      base += N_CTB;
  ushort_t* Wqkvb  = (ushort_t*)base;      base += N_WQ;
  ushort_t* Wob    = (ushort_t*)base;      base += N_WO;
  ushort_t* W1b    = (ushort_t*)base;      base += N_W1;
  ushort_t* W2b    = (ushort_t*)base;      base += N_W2;
  ushort_t* partb  = (ushort_t*)base;      base += N_PT;
  ushort_t* timetb = (ushort_t*)base;      base += N_TT;
  ushort_t* f0tb   = (ushort_t*)base;      base += N_FT;
  ushort_t* xpb    = (ushort_t*)base;

  cvt_bf16<<<(10616832 / 4 + 255) / 256, 256, 0, stream>>>(Wqkv, Wqkvb, 10616832);
  cvt_bf16<<<(3538944 / 4 + 255) / 256, 256, 0, stream>>>(Wo, Wob, 3538944);
  cvt_bf16<<<(9437184 / 4 + 255) / 256, 256, 0, stream>>>(W1, W1b, 9437184);
  cvt_bf16<<<(9437184 / 4 + 255) / 256, 256, 0, stream>>>(W2, W2b, 9437184);
  cvt_bf16<<<(8192 / 4 + 255) / 256, 256, 0, stream>>>(part, partb, 8192);
  cvt_bf16<<<(153856 / 4 + 255) / 256, 256, 0, stream>>>(timet, timetb, 153856);
  cvt_bf16<<<(138240 / 4 + 255) / 256, 256, 0, stream>>>(f0t, f0tb, 138240);

  embed_kernel<<<(ROWS * DIM + 255) / 256, 256, 0, stream>>>(cp, ct, cf, part, f0t, pad, xb);

  for (int l = 0; l < NLAYERS; ++l) {
    // QKV GEMM -> split layout [idx][B][H][S][64], Q pre-scaled
    gemm_bb<<<dim3(TDIM3 / BN, ROWS / BM), 256, 0, stream>>>(
        xb, Wqkvb + (size_t)l * TDIM3 * DIM, bqkv + l * TDIM3,
        bufb, ROWS, TDIM3, DIM, 0, 1);
    attn_mfma<<<dim3(SEQ / QBLK, NHEAD, BATCH), 256, 0, stream>>>(bufb, ctxbb);
    // Wo: raw bf16 out -> bufb (reused); resid handled in ln_bb
    gemm_bb<<<dim3(DIM / BN, ROWS / BM), 256, 0, stream>>>(
        ctxbb, Wob + (size_t)l * DIM * DIM, bo + l * DIM,
        bufb, ROWS, DIM, DIM, 0, 0);
    ln_bb<<<ROWS, 256, 0, stream>>>(bufb, xb, ln1g + l * DIM, ln1b + l * DIM);
    // W1 (relu) -> bufb
    gemm_bb<<<dim3(DFF / BN, ROWS / BM), 256, 0, stream>>>(
        xb, W1b + (size_t)l * DFF * DIM, b1 + l * DFF,
        bufb, ROWS, DFF, DIM, 1, 0);
    // W2 -> ctxbb
    gemm_bb<<<dim3(DIM / BN, ROWS / BM), 256, 0, stream>>>(
        bufb, W2b + (size_t)l * DIM * DFF, b2 + l * DIM,
        ctxbb, ROWS, DIM, DFF, 0, 0);
    ln_bb<<<ROWS, 256, 0, stream>>>(ctxbb, xb, ln2g + l * DIM, ln2b + l * DIM);
  }

  float* out = (float*)d_out;
  gather_pred<<<(PREDROWS * DIM + 255) / 256, 256, 0, stream>>>(xb, xpb);
  head_mfma<<<dim3(1, PREDROWS / BM), 256, 0, stream>>>(xpb, partb, out, 64, 128, DIM, 0);
  head_mfma<<<dim3(5, PREDROWS / BM), 256, 0, stream>>>(xpb, timetb, out + 32768, NUM_TIMES, 256, DIM, 128);
  head_mfma<<<dim3(3, PREDROWS / BM), 256, 0, stream>>>(xpb, f0tb, out + 32768 + 307712, NUM_F0, 384, DIM, 384);
}

// Round 29
// 2690.388 us; speedup vs baseline: 1.0376x; 1.0376x over previous
//
#include <hip/hip_runtime.h>
#include <hip/hip_bf16.h>
#include <math.h>

#define D_P 128
#define D_T 256
#define D_F 384
#define DIM 768
#define NUM_TIMES 601
#define NUM_F0 360
#define NHEAD 12
#define HD 64
#define NLAYERS 6
#define DFF 2048
#define CTX 1024
#define SEQ 1088
#define BATCH 8
#define ROWS (BATCH*SEQ)
#define TDIM3 (3*DIM)
#define PREDROWS 512

typedef unsigned short ushort_t;
typedef __attribute__((ext_vector_type(8))) short bfrag;
typedef __attribute__((ext_vector_type(4))) float f32x4;

// Required template symbol; also the guard-path fill kernel.
__global__ void SequenceModel_30425548325019_kernel(unsigned short* out, int n, unsigned short v) {
  int i = blockIdx.x * 256 + threadIdx.x;
  if (i < n) out[i] = v;
}

__device__ inline short f2bf(float f) {
  unsigned u = __float_as_uint(f);
  unsigned r = (u + 0x7FFFu + ((u >> 16) & 1u)) >> 16;  // RNE
  return (short)r;
}

__device__ inline float bflo(unsigned u) { return __uint_as_float(u << 16); }
__device__ inline float bfhi(unsigned u) { return __uint_as_float(u & 0xFFFF0000u); }
__device__ inline unsigned packbf(float a, float b) {
  return ((unsigned)(ushort_t)f2bf(a)) | (((unsigned)(ushort_t)f2bf(b)) << 16);
}

__device__ inline void gload16(const void* g, void* l) {
  __builtin_amdgcn_global_load_lds(
      (const __attribute__((address_space(1))) unsigned*)g,
      (__attribute__((address_space(3))) unsigned*)l, 16, 0, 0);
}

// ---------------- fp32 -> bf16 bulk convert ----------------
__global__ __launch_bounds__(256) void cvt_bf16(const float* __restrict__ src,
                                                ushort_t* __restrict__ dst, int n) {
  int i = (blockIdx.x * 256 + threadIdx.x) * 4;
  if (i >= n) return;
  float4 v = *(const float4*)(src + i);
  dst[i + 0] = (ushort_t)f2bf(v.x);
  dst[i + 1] = (ushort_t)f2bf(v.y);
  dst[i + 2] = (ushort_t)f2bf(v.z);
  dst[i + 3] = (ushort_t)f2bf(v.w);
}

// ---------------- embedding: writes bf16 xb only ----------------
__global__ __launch_bounds__(256) void embed_kernel(
    const int* __restrict__ cp, const float* __restrict__ ct,
    const int* __restrict__ cf, const float* __restrict__ part,
    const float* __restrict__ f0t, const float* __restrict__ pad,
    ushort_t* __restrict__ xb) {
  int idx = blockIdx.x * 256 + threadIdx.x;
  if (idx >= ROWS * DIM) return;
  int d = idx % DIM;
  int row = idx / DIM;
  int b = row / SEQ, s = row - b * SEQ;
  float v;
  if (s >= CTX) {
    v = pad[d];
  } else if (d < D_P) {
    v = part[cp[b * CTX + s] * D_P + d];
  } else if (d < D_P + D_T) {
    int j = d - D_P;
    int i2 = j >> 1;
    float wk = powf(10000.f, -(float)i2 / (float)D_T) * ((float)D_T / (float)NUM_TIMES);
    float ang = ct[b * CTX + s] * wk;
    v = (j & 1) ? cosf(ang) : sinf(ang);
  } else {
    v = f0t[cf[b * CTX + s] * D_F + (d - D_P - D_T)];
  }
  xb[idx] = (ushort_t)f2bf(v);
}

// ---------------- bf16 MFMA NT GEMM, double-buffered LDS pipeline ----------
#define BM 128
#define BN 128
#define BK 32
// qscale folds softmax 1/sqrt(64) AND log2(e) for exp2-softmax
#define QSCALE 0.1803368801f

__global__ __launch_bounds__(256) void gemm_bb(
    const ushort_t* __restrict__ A, const ushort_t* __restrict__ B,
    const float* __restrict__ bias,
    ushort_t* __restrict__ Cb, int M, int N, int K, int relu, int qscale) {
  __shared__ short As[2][4 * BM * 8];
  __shared__ short Bs[2][4 * BN * 8];
  const int tid = threadIdx.x;
  const int wave = tid >> 6, lane = tid & 63;
  const int wr = wave >> 1, wc = wave & 1;
  const int l15 = lane & 15, l4 = lane >> 4;
  const int m0 = blockIdx.y * BM, n0 = blockIdx.x * BN;
  f32x4 acc[4][4] = {};

  const int u0row = (wave * 64 + lane) & 127, u0kg = (wave * 64 + lane) >> 7;
  const int u1row = (256 + wave * 64 + lane) & 127, u1kg = (256 + wave * 64 + lane) >> 7;
  const ushort_t* Ap0 = A + (size_t)(m0 + u0row) * K + u0kg * 8;
  const ushort_t* Bp0 = B + (size_t)(n0 + u0row) * K + u0kg * 8;
  const ushort_t* Ap1 = A + (size_t)(m0 + u1row) * K + u1kg * 8;
  const ushort_t* Bp1 = B + (size_t)(n0 + u1row) * K + u1kg * 8;
  const int ldsoff0 = (wave * 64) * 8;
  const int ldsoff1 = (256 + wave * 64) * 8;

  gload16(Ap0, &As[0][ldsoff0]);
  gload16(Bp0, &Bs[0][ldsoff0]);
  gload16(Ap1, &As[0][ldsoff1]);
  gload16(Bp1, &Bs[0][ldsoff1]);
  __syncthreads();

  int cur = 0;
  for (int k0 = 0; k0 < K; k0 += BK) {
    if (k0 + BK < K) {
      gload16(Ap0 + k0 + BK, &As[cur ^ 1][ldsoff0]);
      gload16(Bp0 + k0 + BK, &Bs[cur ^ 1][ldsoff0]);
      gload16(Ap1 + k0 + BK, &As[cur ^ 1][ldsoff1]);
      gload16(Bp1 + k0 + BK, &Bs[cur ^ 1][ldsoff1]);
    }
    bfrag a[4], b[4];
    #pragma unroll
    for (int f = 0; f < 4; ++f) {
      a[f] = *(const bfrag*)&As[cur][(l4 * BM + wr * 64 + f * 16 + l15) * 8];
      b[f] = *(const bfrag*)&Bs[cur][(l4 * BN + wc * 64 + f * 16 + l15) * 8];
    }
    __builtin_amdgcn_s_setprio(1);
    #pragma unroll
    for (int i = 0; i < 4; ++i)
      #pragma unroll
      for (int j = 0; j < 4; ++j)
        acc[i][j] = __builtin_amdgcn_mfma_f32_16x16x32_bf16(a[i], b[j], acc[i][j], 0, 0, 0);
    __builtin_amdgcn_s_setprio(0);
    __syncthreads();
    cur ^= 1;
  }
  #pragma unroll
  for (int i = 0; i < 4; ++i) {
    int mbase = m0 + wr * 64 + i * 16 + l4 * 4;
    #pragma unroll
    for (int j = 0; j < 4; ++j) {
      int n = n0 + wc * 64 + j * 16 + l15;
      float bv = bias[n];
      #pragma unroll
      for (int r = 0; r < 4; ++r) {
        int m = mbase + r;
        float v = acc[i][j][r] + bv;
        if (relu) v = fmaxf(v, 0.f);
        if (qscale && n < DIM) v *= QSCALE;
        Cb[(size_t)m * N + n] = (ushort_t)f2bf(v);
      }
    }
  }
}

// ---------------- gather pred rows (bf16) ----------------
__global__ __launch_bounds__(256) void gather_pred(const ushort_t* __restrict__ xb,
                                                   ushort_t* __restrict__ xpb) {
  int idx = blockIdx.x * 256 + threadIdx.x;
  if (idx >= PREDROWS * DIM) return;
  int r = idx / DIM, d = idx - r * DIM;
  int b = r >> 6, rr = r & 63;
  xpb[idx] = xb[(size_t)(b * SEQ + CTX + rr) * DIM + d];
}

// ---------------- head GEMM (bf16 operands, fp32 out, N-guarded stores) ------
__global__ __launch_bounds__(256) void head_mfma(
    const ushort_t* __restrict__ A, const ushort_t* __restrict__ B,
    float* __restrict__ C, int N, int K, int lda, int coloff) {
  __shared__ short As[4 * BM * 8];
  __shared__ short Bs[4 * BN * 8];
  const int tid = threadIdx.x;
  const int wave = tid >> 6, lane = tid & 63;
  const int wr = wave >> 1, wc = wave & 1;
  const int l15 = lane & 15, l4 = lane >> 4;
  const int m0 = blockIdx.y * BM, n0 = blockIdx.x * BN;
  f32x4 acc[4][4] = {};

  for (int k0 = 0; k0 < K; k0 += BK) {
    __syncthreads();
    #pragma unroll
    for (int i = 0; i < 2; ++i) {
      int u = i * 256 + wave * 64 + lane;
      int row = u & 127, kg = u >> 7;
      gload16(A + (size_t)(m0 + row) * lda + coloff + k0 + kg * 8,
              &As[(i * 256 + wave * 64) * 8]);
      gload16(B + (size_t)(n0 + row) * K + k0 + kg * 8,
              &Bs[(i * 256 + wave * 64) * 8]);
    }
    __syncthreads();
    bfrag a[4], b[4];
    #pragma unroll
    for (int f = 0; f < 4; ++f) {
      a[f] = *(const bfrag*)&As[(l4 * BM + wr * 64 + f * 16 + l15) * 8];
      b[f] = *(const bfrag*)&Bs[(l4 * BN + wc * 64 + f * 16 + l15) * 8];
    }
    #pragma unroll
    for (int i = 0; i < 4; ++i)
      #pragma unroll
      for (int j = 0; j < 4; ++j)
        acc[i][j] = __builtin_amdgcn_mfma_f32_16x16x32_bf16(a[i], b[j], acc[i][j], 0, 0, 0);
  }
  #pragma unroll
  for (int i = 0; i < 4; ++i) {
    int mbase = m0 + wr * 64 + i * 16 + l4 * 4;
    #pragma unroll
    for (int j = 0; j < 4; ++j) {
      int n = n0 + wc * 64 + j * 16 + l15;
      if (n >= N) continue;
      #pragma unroll
      for (int r = 0; r < 4; ++r)
        C[(size_t)(mbase + r) * N + n] = acc[i][j][r];
    }
  }
}

// ---------------- MFMA flash attention v9: in-register softmax, KBLK=128 -----
// Grid (17, NHEAD, BATCH). Q,K fragments straight from global (packed QKV);
// V transposed in LDS; softmax in registers; 2 barriers per 128-k tile.
#define QBLK 64
#define KBLK 128
__global__ __launch_bounds__(256) void attn_mfma(const ushort_t* __restrict__ qkv,
                                                 ushort_t* __restrict__ outb) {
  const int qt = blockIdx.x, h = blockIdx.y, b = blockIdx.z;
  const int q0 = qt * QBLK;
  __shared__ char smem[16 * 64 * 9 * 2 * 2];   // Vt + Ps (36,864 B) ; SO overlay fits
  short* Vt = (short*)smem;                    // [kg(16)][d(64)][j(8)+pad]
  short* Ps = (short*)(smem + 16 * 64 * 9 * 2);// [kg(16)][q(64)][j(8)+pad]
  float* SO = (float*)smem;                    // epilogue only (64*65 floats)
  const int tid = threadIdx.x;
  const int wave = tid >> 6, lane = tid & 63;
  const int l15 = lane & 15, l4 = lane >> 4;
  const int qf = wave;

  const size_t qrow_addr = (size_t)(b * SEQ + q0 + qf * 16 + l15) * TDIM3 + h * HD;
  bfrag aq0 = *(const bfrag*)(qkv + qrow_addr + l4 * 8);
  bfrag aq1 = *(const bfrag*)(qkv + qrow_addr + 32 + l4 * 8);

  float mrun[4], lrun[4];
  #pragma unroll
  for (int r = 0; r < 4; ++r) { mrun[r] = -1e30f; lrun[r] = 0.f; }
  f32x4 o[4] = {};
  const int nkt = (q0 < CTX) ? (q0 + QBLK + KBLK - 1) / KBLK : (CTX / KBLK);

  for (int kt = 0; kt < nkt; ++kt) {
    const int k0 = kt * KBLK;
    __syncthreads();   // prev PV done: Vt free
    // stage V transposed (128 rows)
    #pragma unroll
    for (int i = 0; i < 4; ++i) {
      int u = tid + 256 * i;
      int krow = u >> 3, dg = u & 7;
      bfrag vv = *(const bfrag*)(qkv + (size_t)(b * SEQ + k0 + krow) * TDIM3 + 2 * DIM + h * HD + dg * 8);
      int kg = krow >> 3, j = krow & 7;
      #pragma unroll
      for (int e = 0; e < 8; ++e)
        Vt[(kg * 64 + dg * 8 + e) * 9 + j] = vv[e];
    }
    // QK^T: 8 S-frags in registers
    f32x4 s[8];
    #pragma unroll
    for (int jk = 0; jk < 8; ++jk) {
      const size_t krow_addr = (size_t)(b * SEQ + k0 + jk * 16 + l15) * TDIM3 + DIM + h * HD;
      bfrag bk0 = *(const bfrag*)(qkv + krow_addr + l4 * 8);
      bfrag bk1 = *(const bfrag*)(qkv + krow_addr + 32 + l4 * 8);
      f32x4 acc = {};
      acc = __builtin_amdgcn_mfma_f32_16x16x32_bf16(aq0, bk0, acc, 0, 0, 0);
      s[jk] = __builtin_amdgcn_mfma_f32_16x16x32_bf16(aq1, bk1, acc, 0, 0, 0);
    }
    // in-register online softmax (exp2 domain), per q-row r
    #pragma unroll
    for (int r = 0; r < 4; ++r) {
      const int qglob = q0 + qf * 16 + l4 * 4 + r;
      float pv[8];
      float tm = -1e30f;
      #pragma unroll
      for (int jk = 0; jk < 8; ++jk) {
        int kg = k0 + jk * 16 + l15;
        bool allowed = (qglob < CTX) ? (kg <= qglob) : true;
        pv[jk] = allowed ? s[jk][r] : -1e30f;
        tm = fmaxf(tm, pv[jk]);
      }
      tm = fmaxf(tm, __shfl_xor(tm, 1));
      tm = fmaxf(tm, __shfl_xor(tm, 2));
      tm = fmaxf(tm, __shfl_xor(tm, 4));
      tm = fmaxf(tm, __shfl_xor(tm, 8));
      float mn = fmaxf(mrun[r], tm);
      float alpha = exp2f(mrun[r] - mn);
      float ls = 0.f;
      #pragma unroll
      for (int jk = 0; jk < 8; ++jk) { pv[jk] = exp2f(pv[jk] - mn); ls += pv[jk]; }
      ls += __shfl_xor(ls, 1);
      ls += __shfl_xor(ls, 2);
      ls += __shfl_xor(ls, 4);
      ls += __shfl_xor(ls, 8);
      lrun[r] = lrun[r] * alpha + ls;
      mrun[r] = mn;
      #pragma unroll
      for (int df = 0; df < 4; ++df) o[df][r] *= alpha;
      const int qrow = qf * 16 + l4 * 4 + r;
      #pragma unroll
      for (int jk = 0; jk < 8; ++jk) {
        int kgi = jk * 2 + (l15 >> 3), j = l15 & 7;
        Ps[(kgi * 64 + qrow) * 9 + j] = f2bf(pv[jk]);
      }
    }
    __syncthreads();   // Vt staged across waves; Ps complete
    // PV over 128-k (4 chunks of 32)
    #pragma unroll
    for (int c = 0; c < 4; ++c) {
      bfrag pa = *(const bfrag*)&Ps[((c * 4 + l4) * 64 + qf * 16 + l15) * 9];
      #pragma unroll
      for (int df = 0; df < 4; ++df) {
        bfrag v = *(const bfrag*)&Vt[((c * 4 + l4) * 64 + df * 16 + l15) * 9];
        o[df] = __builtin_amdgcn_mfma_f32_16x16x32_bf16(pa, v, o[df], 0, 0, 0);
      }
    }
  }
  // epilogue: normalize in-register, stage via SO (overlaid), coalesced write
  __syncthreads();
  #pragma unroll
  for (int r = 0; r < 4; ++r) {
    float li = 1.f / lrun[r];
    #pragma unroll
    for (int df = 0; df < 4; ++df)
      SO[(qf * 16 + l4 * 4 + r) * 65 + df * 16 + l15] = o[df][r] * li;
  }
  __syncthreads();
  #pragma unroll
  for (int i = 0; i < 2; ++i) {
    int s2 = tid + 256 * i;
    int r = s2 >> 3, kg = s2 & 7;
    ushort_t* dst = outb + (size_t)(b * SEQ + q0 + r) * DIM + h * HD + kg * 8;
    const float* sp = &SO[r * 65 + kg * 8];
    bfrag t;
    #pragma unroll
    for (int e = 0; e < 8; ++e) t[e] = f2bf(sp[e]);
    *(bfrag*)dst = t;
  }
}

// ---------------- fused residual+LN, bf16-only stream: xb = LN(xb + raw) -----
__global__ __launch_bounds__(256) void ln_bb(const ushort_t* __restrict__ raw,
                                             ushort_t* __restrict__ xb,
                                             const float* __restrict__ g,
                                             const float* __restrict__ bb) {
  const int row = blockIdx.x;
  unsigned* pu = (unsigned*)(xb + (size_t)row * DIM);
  const unsigned* qu = (const unsigned*)(raw + (size_t)row * DIM);
  const float2* g2 = (const float2*)g;
  const float2* b2 = (const float2*)bb;
  const int tid = threadIdx.x;

  unsigned x0 = pu[tid], r0 = qu[tid];
  float v00 = bflo(x0) + bflo(r0);
  float v01 = bfhi(x0) + bfhi(r0);
  float v10 = 0.f, v11 = 0.f;
  if (tid < 128) {
    unsigned x1 = pu[256 + tid], r1 = qu[256 + tid];
    v10 = bflo(x1) + bflo(r1);
    v11 = bfhi(x1) + bfhi(r1);
  }
  float s1 = v00 + v01 + v10 + v11;
  float s2 = v00 * v00 + v01 * v01 + v10 * v10 + v11 * v11;
  #pragma unroll
  for (int off = 32; off >= 1; off >>= 1) {
    s1 += __shfl_down(s1, off);
    s2 += __shfl_down(s2, off);
  }
  __shared__ float r1s[4], r2s[4];
  int wid = tid >> 6;
  if ((tid & 63) == 0) { r1s[wid] = s1; r2s[wid] = s2; }
  __syncthreads();
  s1 = r1s[0] + r1s[1] + r1s[2] + r1s[3];
  s2 = r2s[0] + r2s[1] + r2s[2] + r2s[3];
  const float mu = s1 * (1.f / DIM);
  const float var = s2 * (1.f / DIM) - mu * mu;
  const float rs = rsqrtf(var + 1e-5f);
  float2 ga = g2[tid], ba = b2[tid];
  float o00 = (v00 - mu) * rs * ga.x + ba.x;
  float o01 = (v01 - mu) * rs * ga.y + ba.y;
  pu[tid] = packbf(o00, o01);
  if (tid < 128) {
    float2 gb = g2[256 + tid], bbv = b2[256 + tid];
    float o10 = (v10 - mu) * rs * gb.x + bbv.x;
    float o11 = (v11 - mu) * rs * gb.y + bbv.y;
    pu[256 + tid] = packbf(o10, o11);
  }
}

extern "C" void kernel_launch(void* const* d_in, const int* in_sizes, int n_in,
                              void* d_out, int out_size, void* d_ws, size_t ws_size,
                              hipStream_t stream) {
  const size_t N_XB   = (size_t)ROWS * DIM / 2;
  const size_t N_BUFB = (size_t)ROWS * TDIM3 / 2;
  const size_t N_CTB  = (size_t)ROWS * DIM / 2;
  const size_t N_WQ   = 10616832 / 2;
  const size_t N_WO   = 3538944 / 2;
  const size_t N_W1   = 9437184 / 2;
  const size_t N_W2   = 9437184 / 2;
  const size_t N_PT   = 8192 / 2;
  const size_t N_TT   = 153856 / 2;
  const size_t N_FT   = 138240 / 2;
  const size_t N_XPB  = (size_t)PREDROWS * DIM / 2;
  size_t need = (N_XB + N_BUFB + N_CTB + N_WQ + N_WO + N_W1 + N_W2 +
                 N_PT + N_TT + N_FT + N_XPB) * sizeof(float);
  if (ws_size < need) {
    SequenceModel_30425548325019_kernel<<<(out_size + 255) / 256, 256, 0, stream>>>(
        (unsigned short*)d_out, out_size, (unsigned short)0x4280);
    return;
  }

  const int*   cp    = (const int*)d_in[0];
  const float* ct    = (const float*)d_in[1];
  const int*   cf    = (const int*)d_in[2];
  const float* part  = (const float*)d_in[3];
  const float* timet = (const float*)d_in[4];
  const float* f0t   = (const float*)d_in[5];
  const float* pad   = (const float*)d_in[6];
  const float* Wqkv  = (const float*)d_in[7];
  const float* bqkv  = (const float*)d_in[8];
  const float* Wo    = (const float*)d_in[9];
  const float* bo    = (const float*)d_in[10];
  const float* ln1g  = (const float*)d_in[11];
  const float* ln1b  = (const float*)d_in[12];
  const float* W1    = (const float*)d_in[13];
  const float* b1    = (const float*)d_in[14];
  const float* W2    = (const float*)d_in[15];
  const float* b2    = (const float*)d_in[16];
  const float* ln2g  = (const float*)d_in[17];
  const float* ln2b  = (const float*)d_in[18];

  float* base = (float*)d_ws;
  ushort_t* xb     = (ushort_t*)base;      base += N_XB;
  ushort_t* bufb   = (ushort_t*)base;      base += N_BUFB;
  ushort_t* ctxbb  = (ushort_t*)base;      base += N_CTB;
  ushort_t* Wqkvb  = (ushort_t*)base;      base += N_WQ;
  ushort_t* Wob    = (ushort_t*)base;      base += N_WO;
  ushort_t* W1b    = (ushort_t*)base;      base += N_W1;
  ushort_t* W2b    = (ushort_t*)base;      base += N_W2;
  ushort_t* partb  = (ushort_t*)base;      base += N_PT;
  ushort_t* timetb = (ushort_t*)base;      base += N_TT;
  ushort_t* f0tb   = (ushort_t*)base;      base += N_FT;
  ushort_t* xpb    = (ushort_t*)base;

  cvt_bf16<<<(10616832 / 4 + 255) / 256, 256, 0, stream>>>(Wqkv, Wqkvb, 10616832);
  cvt_bf16<<<(3538944 / 4 + 255) / 256, 256, 0, stream>>>(Wo, Wob, 3538944);
  cvt_bf16<<<(9437184 / 4 + 255) / 256, 256, 0, stream>>>(W1, W1b, 9437184);
  cvt_bf16<<<(9437184 / 4 + 255) / 256, 256, 0, stream>>>(W2, W2b, 9437184);
  cvt_bf16<<<(8192 / 4 + 255) / 256, 256, 0, stream>>>(part, partb, 8192);
  cvt_bf16<<<(153856 / 4 + 255) / 256, 256, 0, stream>>>(timet, timetb, 153856);
  cvt_bf16<<<(138240 / 4 + 255) / 256, 256, 0, stream>>>(f0t, f0tb, 138240);

  embed_kernel<<<(ROWS * DIM + 255) / 256, 256, 0, stream>>>(cp, ct, cf, part, f0t, pad, xb);

  for (int l = 0; l < NLAYERS; ++l) {
    // QKV (bf16 out, Q pre-scaled by 0.125*log2e for exp2 softmax)
    gemm_bb<<<dim3(TDIM3 / BN, ROWS / BM), 256, 0, stream>>>(
        xb, Wqkvb + (size_t)l * TDIM3 * DIM, bqkv + l * TDIM3,
        bufb, ROWS, TDIM3, DIM, 0, 1);
    attn_mfma<<<dim3(SEQ / QBLK, NHEAD, BATCH), 256, 0, stream>>>(bufb, ctxbb);
    // Wo: raw bf16 out -> bufb; resid handled in ln_bb
    gemm_bb<<<dim3(DIM / BN, ROWS / BM), 256, 0, stream>>>(
        ctxbb, Wob + (size_t)l * DIM * DIM, bo + l * DIM,
        bufb, ROWS, DIM, DIM, 0, 0);
    ln_bb<<<ROWS, 256, 0, stream>>>(bufb, xb, ln1g + l * DIM, ln1b + l * DIM);
    // W1 (relu, bf16 out) -> bufb
    gemm_bb<<<dim3(DFF / BN, ROWS / BM), 256, 0, stream>>>(
        xb, W1b + (size_t)l * DFF * DIM, b1 + l * DFF,
        bufb, ROWS, DFF, DIM, 1, 0);
    // W2: raw bf16 out -> ctxbb
    gemm_bb<<<dim3(DIM / BN, ROWS / BM), 256, 0, stream>>>(
        bufb, W2b + (size_t)l * DIM * DFF, b2 + l * DIM,
        ctxbb, ROWS, DIM, DFF, 0, 0);
    ln_bb<<<ROWS, 256, 0, stream>>>(ctxbb, xb, ln2g + l * DIM, ln2b + l * DIM);
  }

  float* out = (float*)d_out;
  gather_pred<<<(PREDROWS * DIM + 255) / 256, 256, 0, stream>>>(xb, xpb);
  head_mfma<<<dim3(1, PREDROWS / BM), 256, 0, stream>>>(xpb, partb, out, 64, 128, DIM, 0);
  head_mfma<<<dim3(5, PREDROWS / BM), 256, 0, stream>>>(xpb, timetb, out + 32768, NUM_TIMES, 256, DIM, 128);
  head_mfma<<<dim3(3, PREDROWS / BM), 256, 0, stream>>>(xpb, f0tb, out + 32768 + 307712, NUM_F0, 384, DIM, 384);
}

// Round 30
// 2656.389 us; speedup vs baseline: 1.0509x; 1.0128x over previous
//
#include <hip/hip_runtime.h>
#include <hip/hip_bf16.h>
#include <math.h>

#define D_P 128
#define D_T 256
#define D_F 384
#define DIM 768
#define NUM_TIMES 601
#define NUM_F0 360
#define NHEAD 12
#define HD 64
#define NLAYERS 6
#define DFF 2048
#define CTX 1024
#define SEQ 1088
#define BATCH 8
#define ROWS (BATCH*SEQ)
#define TDIM3 (3*DIM)
#define PREDROWS 512

typedef unsigned short ushort_t;
typedef __attribute__((ext_vector_type(8))) short bfrag;
typedef __attribute__((ext_vector_type(4))) float f32x4;

// Required template symbol; also the guard-path fill kernel.
__global__ void SequenceModel_30425548325019_kernel(unsigned short* out, int n, unsigned short v) {
  int i = blockIdx.x * 256 + threadIdx.x;
  if (i < n) out[i] = v;
}

__device__ inline short f2bf(float f) {
  unsigned u = __float_as_uint(f);
  unsigned r = (u + 0x7FFFu + ((u >> 16) & 1u)) >> 16;  // RNE
  return (short)r;
}

__device__ inline float bflo(unsigned u) { return __uint_as_float(u << 16); }
__device__ inline float bfhi(unsigned u) { return __uint_as_float(u & 0xFFFF0000u); }
__device__ inline unsigned packbf(float a, float b) {
  return ((unsigned)(ushort_t)f2bf(a)) | (((unsigned)(ushort_t)f2bf(b)) << 16);
}

__device__ inline void gload16(const void* g, void* l) {
  __builtin_amdgcn_global_load_lds(
      (const __attribute__((address_space(1))) unsigned*)g,
      (__attribute__((address_space(3))) unsigned*)l, 16, 0, 0);
}

// ---------------- fp32 -> bf16 bulk convert ----------------
__global__ __launch_bounds__(256) void cvt_bf16(const float* __restrict__ src,
                                                ushort_t* __restrict__ dst, int n) {
  int i = (blockIdx.x * 256 + threadIdx.x) * 4;
  if (i >= n) return;
  float4 v = *(const float4*)(src + i);
  dst[i + 0] = (ushort_t)f2bf(v.x);
  dst[i + 1] = (ushort_t)f2bf(v.y);
  dst[i + 2] = (ushort_t)f2bf(v.z);
  dst[i + 3] = (ushort_t)f2bf(v.w);
}

// ---------------- embedding: writes bf16 xb only ----------------
__global__ __launch_bounds__(256) void embed_kernel(
    const int* __restrict__ cp, const float* __restrict__ ct,
    const int* __restrict__ cf, const float* __restrict__ part,
    const float* __restrict__ f0t, const float* __restrict__ pad,
    ushort_t* __restrict__ xb) {
  int idx = blockIdx.x * 256 + threadIdx.x;
  if (idx >= ROWS * DIM) return;
  int d = idx % DIM;
  int row = idx / DIM;
  int b = row / SEQ, s = row - b * SEQ;
  float v;
  if (s >= CTX) {
    v = pad[d];
  } else if (d < D_P) {
    v = part[cp[b * CTX + s] * D_P + d];
  } else if (d < D_P + D_T) {
    int j = d - D_P;
    int i2 = j >> 1;
    float wk = powf(10000.f, -(float)i2 / (float)D_T) * ((float)D_T / (float)NUM_TIMES);
    float ang = ct[b * CTX + s] * wk;
    v = (j & 1) ? cosf(ang) : sinf(ang);
  } else {
    v = f0t[cf[b * CTX + s] * D_F + (d - D_P - D_T)];
  }
  xb[idx] = (ushort_t)f2bf(v);
}

// ---------------- bf16 MFMA NT GEMM, double-buffered LDS pipeline ----------
#define BM 128
#define BN 128
#define BK 32
// qscale folds softmax 1/sqrt(64) AND log2(e) for exp2-softmax
#define QSCALE 0.1803368801f

__global__ __launch_bounds__(256) void gemm_bb(
    const ushort_t* __restrict__ A, const ushort_t* __restrict__ B,
    const float* __restrict__ bias,
    ushort_t* __restrict__ Cb, int M, int N, int K, int relu, int qscale) {
  __shared__ short As[2][4 * BM * 8];
  __shared__ short Bs[2][4 * BN * 8];
  const int tid = threadIdx.x;
  const int wave = tid >> 6, lane = tid & 63;
  const int wr = wave >> 1, wc = wave & 1;
  const int l15 = lane & 15, l4 = lane >> 4;
  const int m0 = blockIdx.y * BM, n0 = blockIdx.x * BN;
  f32x4 acc[4][4] = {};

  const int u0row = (wave * 64 + lane) & 127, u0kg = (wave * 64 + lane) >> 7;
  const int u1row = (256 + wave * 64 + lane) & 127, u1kg = (256 + wave * 64 + lane) >> 7;
  const ushort_t* Ap0 = A + (size_t)(m0 + u0row) * K + u0kg * 8;
  const ushort_t* Bp0 = B + (size_t)(n0 + u0row) * K + u0kg * 8;
  const ushort_t* Ap1 = A + (size_t)(m0 + u1row) * K + u1kg * 8;
  const ushort_t* Bp1 = B + (size_t)(n0 + u1row) * K + u1kg * 8;
  const int ldsoff0 = (wave * 64) * 8;
  const int ldsoff1 = (256 + wave * 64) * 8;

  gload16(Ap0, &As[0][ldsoff0]);
  gload16(Bp0, &Bs[0][ldsoff0]);
  gload16(Ap1, &As[0][ldsoff1]);
  gload16(Bp1, &Bs[0][ldsoff1]);
  __syncthreads();

  int cur = 0;
  for (int k0 = 0; k0 < K; k0 += BK) {
    if (k0 + BK < K) {
      gload16(Ap0 + k0 + BK, &As[cur ^ 1][ldsoff0]);
      gload16(Bp0 + k0 + BK, &Bs[cur ^ 1][ldsoff0]);
      gload16(Ap1 + k0 + BK, &As[cur ^ 1][ldsoff1]);
      gload16(Bp1 + k0 + BK, &Bs[cur ^ 1][ldsoff1]);
    }
    bfrag a[4], b[4];
    #pragma unroll
    for (int f = 0; f < 4; ++f) {
      a[f] = *(const bfrag*)&As[cur][(l4 * BM + wr * 64 + f * 16 + l15) * 8];
      b[f] = *(const bfrag*)&Bs[cur][(l4 * BN + wc * 64 + f * 16 + l15) * 8];
    }
    __builtin_amdgcn_s_setprio(1);
    #pragma unroll
    for (int i = 0; i < 4; ++i)
      #pragma unroll
      for (int j = 0; j < 4; ++j)
        acc[i][j] = __builtin_amdgcn_mfma_f32_16x16x32_bf16(a[i], b[j], acc[i][j], 0, 0, 0);
    __builtin_amdgcn_s_setprio(0);
    __syncthreads();
    cur ^= 1;
  }
  #pragma unroll
  for (int i = 0; i < 4; ++i) {
    int mbase = m0 + wr * 64 + i * 16 + l4 * 4;
    #pragma unroll
    for (int j = 0; j < 4; ++j) {
      int n = n0 + wc * 64 + j * 16 + l15;
      float bv = bias[n];
      #pragma unroll
      for (int r = 0; r < 4; ++r) {
        int m = mbase + r;
        float v = acc[i][j][r] + bv;
        if (relu) v = fmaxf(v, 0.f);
        if (qscale && n < DIM) v *= QSCALE;
        Cb[(size_t)m * N + n] = (ushort_t)f2bf(v);
      }
    }
  }
}

// ---------------- gather pred rows (bf16) ----------------
__global__ __launch_bounds__(256) void gather_pred(const ushort_t* __restrict__ xb,
                                                   ushort_t* __restrict__ xpb) {
  int idx = blockIdx.x * 256 + threadIdx.x;
  if (idx >= PREDROWS * DIM) return;
  int r = idx / DIM, d = idx - r * DIM;
  int b = r >> 6, rr = r & 63;
  xpb[idx] = xb[(size_t)(b * SEQ + CTX + rr) * DIM + d];
}

// ---------------- head GEMM (bf16 operands, fp32 out, N-guarded stores) ------
__global__ __launch_bounds__(256) void head_mfma(
    const ushort_t* __restrict__ A, const ushort_t* __restrict__ B,
    float* __restrict__ C, int N, int K, int lda, int coloff) {
  __shared__ short As[4 * BM * 8];
  __shared__ short Bs[4 * BN * 8];
  const int tid = threadIdx.x;
  const int wave = tid >> 6, lane = tid & 63;
  const int wr = wave >> 1, wc = wave & 1;
  const int l15 = lane & 15, l4 = lane >> 4;
  const int m0 = blockIdx.y * BM, n0 = blockIdx.x * BN;
  f32x4 acc[4][4] = {};

  for (int k0 = 0; k0 < K; k0 += BK) {
    __syncthreads();
    #pragma unroll
    for (int i = 0; i < 2; ++i) {
      int u = i * 256 + wave * 64 + lane;
      int row = u & 127, kg = u >> 7;
      gload16(A + (size_t)(m0 + row) * lda + coloff + k0 + kg * 8,
              &As[(i * 256 + wave * 64) * 8]);
      gload16(B + (size_t)(n0 + row) * K + k0 + kg * 8,
              &Bs[(i * 256 + wave * 64) * 8]);
    }
    __syncthreads();
    bfrag a[4], b[4];
    #pragma unroll
    for (int f = 0; f < 4; ++f) {
      a[f] = *(const bfrag*)&As[(l4 * BM + wr * 64 + f * 16 + l15) * 8];
      b[f] = *(const bfrag*)&Bs[(l4 * BN + wc * 64 + f * 16 + l15) * 8];
    }
    #pragma unroll
    for (int i = 0; i < 4; ++i)
      #pragma unroll
      for (int j = 0; j < 4; ++j)
        acc[i][j] = __builtin_amdgcn_mfma_f32_16x16x32_bf16(a[i], b[j], acc[i][j], 0, 0, 0);
  }
  #pragma unroll
  for (int i = 0; i < 4; ++i) {
    int mbase = m0 + wr * 64 + i * 16 + l4 * 4;
    #pragma unroll
    for (int j = 0; j < 4; ++j) {
      int n = n0 + wc * 64 + j * 16 + l15;
      if (n >= N) continue;
      #pragma unroll
      for (int r = 0; r < 4; ++r)
        C[(size_t)(mbase + r) * N + n] = acc[i][j][r];
    }
  }
}

// ---------------- MFMA flash attention v10: v9 + LPT dispatch order ----------
// Grid (17, NHEAD, BATCH); qt = 16 - blockIdx.x so longest blocks launch FIRST
// (anti-tail / LPT packing). In-register softmax; KBLK=128; 2 barriers/tile.
#define QBLK 64
#define KBLK 128
__global__ __launch_bounds__(256) void attn_mfma(const ushort_t* __restrict__ qkv,
                                                 ushort_t* __restrict__ outb) {
  const int qt = (int)gridDim.x - 1 - (int)blockIdx.x;   // LPT: long blocks first
  const int h = blockIdx.y, b = blockIdx.z;
  const int q0 = qt * QBLK;
  __shared__ char smem[16 * 64 * 9 * 2 * 2];   // Vt + Ps (36,864 B) ; SO overlay fits
  short* Vt = (short*)smem;                    // [kg(16)][d(64)][j(8)+pad]
  short* Ps = (short*)(smem + 16 * 64 * 9 * 2);// [kg(16)][q(64)][j(8)+pad]
  float* SO = (float*)smem;                    // epilogue only (64*65 floats)
  const int tid = threadIdx.x;
  const int wave = tid >> 6, lane = tid & 63;
  const int l15 = lane & 15, l4 = lane >> 4;
  const int qf = wave;

  const size_t qrow_addr = (size_t)(b * SEQ + q0 + qf * 16 + l15) * TDIM3 + h * HD;
  bfrag aq0 = *(const bfrag*)(qkv + qrow_addr + l4 * 8);
  bfrag aq1 = *(const bfrag*)(qkv + qrow_addr + 32 + l4 * 8);

  float mrun[4], lrun[4];
  #pragma unroll
  for (int r = 0; r < 4; ++r) { mrun[r] = -1e30f; lrun[r] = 0.f; }
  f32x4 o[4] = {};
  const int nkt = (q0 < CTX) ? (q0 + QBLK + KBLK - 1) / KBLK : (CTX / KBLK);

  for (int kt = 0; kt < nkt; ++kt) {
    const int k0 = kt * KBLK;
    __syncthreads();   // prev PV done: Vt free
    // stage V transposed (128 rows)
    #pragma unroll
    for (int i = 0; i < 4; ++i) {
      int u = tid + 256 * i;
      int krow = u >> 3, dg = u & 7;
      bfrag vv = *(const bfrag*)(qkv + (size_t)(b * SEQ + k0 + krow) * TDIM3 + 2 * DIM + h * HD + dg * 8);
      int kg = krow >> 3, j = krow & 7;
      #pragma unroll
      for (int e = 0; e < 8; ++e)
        Vt[(kg * 64 + dg * 8 + e) * 9 + j] = vv[e];
    }
    // QK^T: 8 S-frags in registers
    f32x4 s[8];
    #pragma unroll
    for (int jk = 0; jk < 8; ++jk) {
      const size_t krow_addr = (size_t)(b * SEQ + k0 + jk * 16 + l15) * TDIM3 + DIM + h * HD;
      bfrag bk0 = *(const bfrag*)(qkv + krow_addr + l4 * 8);
      bfrag bk1 = *(const bfrag*)(qkv + krow_addr + 32 + l4 * 8);
      f32x4 acc = {};
      acc = __builtin_amdgcn_mfma_f32_16x16x32_bf16(aq0, bk0, acc, 0, 0, 0);
      s[jk] = __builtin_amdgcn_mfma_f32_16x16x32_bf16(aq1, bk1, acc, 0, 0, 0);
    }
    // in-register online softmax (exp2 domain), per q-row r
    #pragma unroll
    for (int r = 0; r < 4; ++r) {
      const int qglob = q0 + qf * 16 + l4 * 4 + r;
      float pv[8];
      float tm = -1e30f;
      #pragma unroll
      for (int jk = 0; jk < 8; ++jk) {
        int kg = k0 + jk * 16 + l15;
        bool allowed = (qglob < CTX) ? (kg <= qglob) : true;
        pv[jk] = allowed ? s[jk][r] : -1e30f;
        tm = fmaxf(tm, pv[jk]);
      }
      tm = fmaxf(tm, __shfl_xor(tm, 1));
      tm = fmaxf(tm, __shfl_xor(tm, 2));
      tm = fmaxf(tm, __shfl_xor(tm, 4));
      tm = fmaxf(tm, __shfl_xor(tm, 8));
      float mn = fmaxf(mrun[r], tm);
      float alpha = exp2f(mrun[r] - mn);
      float ls = 0.f;
      #pragma unroll
      for (int jk = 0; jk < 8; ++jk) { pv[jk] = exp2f(pv[jk] - mn); ls += pv[jk]; }
      ls += __shfl_xor(ls, 1);
      ls += __shfl_xor(ls, 2);
      ls += __shfl_xor(ls, 4);
      ls += __shfl_xor(ls, 8);
      lrun[r] = lrun[r] * alpha + ls;
      mrun[r] = mn;
      #pragma unroll
      for (int df = 0; df < 4; ++df) o[df][r] *= alpha;
      const int qrow = qf * 16 + l4 * 4 + r;
      #pragma unroll
      for (int jk = 0; jk < 8; ++jk) {
        int kgi = jk * 2 + (l15 >> 3), j = l15 & 7;
        Ps[(kgi * 64 + qrow) * 9 + j] = f2bf(pv[jk]);
      }
    }
    __syncthreads();   // Vt staged across waves; Ps complete
    // PV over 128-k (4 chunks of 32)
    #pragma unroll
    for (int c = 0; c < 4; ++c) {
      bfrag pa = *(const bfrag*)&Ps[((c * 4 + l4) * 64 + qf * 16 + l15) * 9];
      #pragma unroll
      for (int df = 0; df < 4; ++df) {
        bfrag v = *(const bfrag*)&Vt[((c * 4 + l4) * 64 + df * 16 + l15) * 9];
        o[df] = __builtin_amdgcn_mfma_f32_16x16x32_bf16(pa, v, o[df], 0, 0, 0);
      }
    }
  }
  // epilogue: normalize in-register, stage via SO (overlaid), coalesced write
  __syncthreads();
  #pragma unroll
  for (int r = 0; r < 4; ++r) {
    float li = 1.f / lrun[r];
    #pragma unroll
    for (int df = 0; df < 4; ++df)
      SO[(qf * 16 + l4 * 4 + r) * 65 + df * 16 + l15] = o[df][r] * li;
  }
  __syncthreads();
  #pragma unroll
  for (int i = 0; i < 2; ++i) {
    int s2 = tid + 256 * i;
    int r = s2 >> 3, kg = s2 & 7;
    ushort_t* dst = outb + (size_t)(b * SEQ + q0 + r) * DIM + h * HD + kg * 8;
    const float* sp = &SO[r * 65 + kg * 8];
    bfrag t;
    #pragma unroll
    for (int e = 0; e < 8; ++e) t[e] = f2bf(sp[e]);
    *(bfrag*)dst = t;
  }
}

// ---------------- fused residual+LN, bf16-only stream: xb = LN(xb + raw) -----
__global__ __launch_bounds__(256) void ln_bb(const ushort_t* __restrict__ raw,
                                             ushort_t* __restrict__ xb,
                                             const float* __restrict__ g,
                                             const float* __restrict__ bb) {
  const int row = blockIdx.x;
  unsigned* pu = (unsigned*)(xb + (size_t)row * DIM);
  const unsigned* qu = (const unsigned*)(raw + (size_t)row * DIM);
  const float2* g2 = (const float2*)g;
  const float2* b2 = (const float2*)bb;
  const int tid = threadIdx.x;

  unsigned x0 = pu[tid], r0 = qu[tid];
  float v00 = bflo(x0) + bflo(r0);
  float v01 = bfhi(x0) + bfhi(r0);
  float v10 = 0.f, v11 = 0.f;
  if (tid < 128) {
    unsigned x1 = pu[256 + tid], r1 = qu[256 + tid];
    v10 = bflo(x1) + bflo(r1);
    v11 = bfhi(x1) + bfhi(r1);
  }
  float s1 = v00 + v01 + v10 + v11;
  float s2 = v00 * v00 + v01 * v01 + v10 * v10 + v11 * v11;
  #pragma unroll
  for (int off = 32; off >= 1; off >>= 1) {
    s1 += __shfl_down(s1, off);
    s2 += __shfl_down(s2, off);
  }
  __shared__ float r1s[4], r2s[4];
  int wid = tid >> 6;
  if ((tid & 63) == 0) { r1s[wid] = s1; r2s[wid] = s2; }
  __syncthreads();
  s1 = r1s[0] + r1s[1] + r1s[2] + r1s[3];
  s2 = r2s[0] + r2s[1] + r2s[2] + r2s[3];
  const float mu = s1 * (1.f / DIM);
  const float var = s2 * (1.f / DIM) - mu * mu;
  const float rs = rsqrtf(var + 1e-5f);
  float2 ga = g2[tid], ba = b2[tid];
  float o00 = (v00 - mu) * rs * ga.x + ba.x;
  float o01 = (v01 - mu) * rs * ga.y + ba.y;
  pu[tid] = packbf(o00, o01);
  if (tid < 128) {
    float2 gb = g2[256 + tid], bbv = b2[256 + tid];
    float o10 = (v10 - mu) * rs * gb.x + bbv.x;
    float o11 = (v11 - mu) * rs * gb.y + bbv.y;
    pu[256 + tid] = packbf(o10, o11);
  }
}

extern "C" void kernel_launch(void* const* d_in, const int* in_sizes, int n_in,
                              void* d_out, int out_size, void* d_ws, size_t ws_size,
                              hipStream_t stream) {
  const size_t N_XB   = (size_t)ROWS * DIM / 2;
  const size_t N_BUFB = (size_t)ROWS * TDIM3 / 2;
  const size_t N_CTB  = (size_t)ROWS * DIM / 2;
  const size_t N_WQ   = 10616832 / 2;
  const size_t N_WO   = 3538944 / 2;
  const size_t N_W1   = 9437184 / 2;
  const size_t N_W2   = 9437184 / 2;
  const size_t N_PT   = 8192 / 2;
  const size_t N_TT   = 153856 / 2;
  const size_t N_FT   = 138240 / 2;
  const size_t N_XPB  = (size_t)PREDROWS * DIM / 2;
  size_t need = (N_XB + N_BUFB + N_CTB + N_WQ + N_WO + N_W1 + N_W2 +
                 N_PT + N_TT + N_FT + N_XPB) * sizeof(float);
  if (ws_size < need) {
    SequenceModel_30425548325019_kernel<<<(out_size + 255) / 256, 256, 0, stream>>>(
        (unsigned short*)d_out, out_size, (unsigned short)0x4280);
    return;
  }

  const int*   cp    = (const int*)d_in[0];
  const float* ct    = (const float*)d_in[1];
  const int*   cf    = (const int*)d_in[2];
  const float* part  = (const float*)d_in[3];
  const float* timet = (const float*)d_in[4];
  const float* f0t   = (const float*)d_in[5];
  const float* pad   = (const float*)d_in[6];
  const float* Wqkv  = (const float*)d_in[7];
  const float* bqkv  = (const float*)d_in[8];
  const float* Wo    = (const float*)d_in[9];
  const float* bo    = (const float*)d_in[10];
  const float* ln1g  = (const float*)d_in[11];
  const float* ln1b  = (const float*)d_in[12];
  const float* W1    = (const float*)d_in[13];
  const float* b1    = (const float*)d_in[14];
  const float* W2    = (const float*)d_in[15];
  const float* b2    = (const float*)d_in[16];
  const float* ln2g  = (const float*)d_in[17];
  const float* ln2b  = (const float*)d_in[18];

  float* base = (float*)d_ws;
  ushort_t* xb     = (ushort_t*)base;      base += N_XB;
  ushort_t* bufb   = (ushort_t*)base;      base += N_BUFB;
  ushort_t* ctxbb  = (ushort_t*)base;      base += N_CTB;
  ushort_t* Wqkvb  = (ushort_t*)base;      base += N_WQ;
  ushort_t* Wob    = (ushort_t*)base;      base += N_WO;
  ushort_t* W1b    = (ushort_t*)base;      base += N_W1;
  ushort_t* W2b    = (ushort_t*)base;      base += N_W2;
  ushort_t* partb  = (ushort_t*)base;      base += N_PT;
  ushort_t* timetb = (ushort_t*)base;      base += N_TT;
  ushort_t* f0tb   = (ushort_t*)base;      base += N_FT;
  ushort_t* xpb    = (ushort_t*)base;

  cvt_bf16<<<(10616832 / 4 + 255) / 256, 256, 0, stream>>>(Wqkv, Wqkvb, 10616832);
  cvt_bf16<<<(3538944 / 4 + 255) / 256, 256, 0, stream>>>(Wo, Wob, 3538944);
  cvt_bf16<<<(9437184 / 4 + 255) / 256, 256, 0, stream>>>(W1, W1b, 9437184);
  cvt_bf16<<<(9437184 / 4 + 255) / 256, 256, 0, stream>>>(W2, W2b, 9437184);
  cvt_bf16<<<(8192 / 4 + 255) / 256, 256, 0, stream>>>(part, partb, 8192);
  cvt_bf16<<<(153856 / 4 + 255) / 256, 256, 0, stream>>>(timet, timetb, 153856);
  cvt_bf16<<<(138240 / 4 + 255) / 256, 256, 0, stream>>>(f0t, f0tb, 138240);

  embed_kernel<<<(ROWS * DIM + 255) / 256, 256, 0, stream>>>(cp, ct, cf, part, f0t, pad, xb);

  for (int l = 0; l < NLAYERS; ++l) {
    // QKV (bf16 out, Q pre-scaled by 0.125*log2e for exp2 softmax)
    gemm_bb<<<dim3(TDIM3 / BN, ROWS / BM), 256, 0, stream>>>(
        xb, Wqkvb + (size_t)l * TDIM3 * DIM, bqkv + l * TDIM3,
        bufb, ROWS, TDIM3, DIM, 0, 1);
    attn_mfma<<<dim3(SEQ / QBLK, NHEAD, BATCH), 256, 0, stream>>>(bufb, ctxbb);
    // Wo: raw bf16 out -> bufb; resid handled in ln_bb
    gemm_bb<<<dim3(DIM / BN, ROWS / BM), 256, 0, stream>>>(
        ctxbb, Wob + (size_t)l * DIM * DIM, bo + l * DIM,
        bufb, ROWS, DIM, DIM, 0, 0);
    ln_bb<<<ROWS, 256, 0, stream>>>(bufb, xb, ln1g + l * DIM, ln1b + l * DIM);
    // W1 (relu, bf16 out) -> bufb
    gemm_bb<<<dim3(DFF / BN, ROWS / BM), 256, 0, stream>>>(
        xb, W1b + (size_t)l * DFF * DIM, b1 + l * DFF,
        bufb, ROWS, DFF, DIM, 1, 0);
    // W2: raw bf16 out -> ctxbb
    gemm_bb<<<dim3(DIM / BN, ROWS / BM), 256, 0, stream>>>(
        bufb, W2b + (size_t)l * DIM * DFF, b2 + l * DIM,
        ctxbb, ROWS, DIM, DFF, 0, 0);
    ln_bb<<<ROWS, 256, 0, stream>>>(ctxbb, xb, ln2g + l * DIM, ln2b + l * DIM);
  }

  float* out = (float*)d_out;
  gather_pred<<<(PREDROWS * DIM + 255) / 256, 256, 0, stream>>>(xb, xpb);
  head_mfma<<<dim3(1, PREDROWS / BM), 256, 0, stream>>>(xpb, partb, out, 64, 128, DIM, 0);
  head_mfma<<<dim3(5, PREDROWS / BM), 256, 0, stream>>>(xpb, timetb, out + 32768, NUM_TIMES, 256, DIM, 128);
  head_mfma<<<dim3(3, PREDROWS / BM), 256, 0, stream>>>(xpb, f0tb, out + 32768 + 307712, NUM_F0, 384, DIM, 384);
}

// Round 31
// 2576.433 us; speedup vs baseline: 1.0835x; 1.0310x over previous
//
#include <hip/hip_runtime.h>
#include <hip/hip_bf16.h>
#include <math.h>

#define D_P 128
#define D_T 256
#define D_F 384
#define DIM 768
#define NUM_TIMES 601
#define NUM_F0 360
#define NHEAD 12
#define HD 64
#define NLAYERS 6
#define DFF 2048
#define CTX 1024
#define SEQ 1088
#define BATCH 8
#define ROWS (BATCH*SEQ)
#define TDIM3 (3*DIM)
#define PREDROWS 512

typedef unsigned short ushort_t;
typedef __attribute__((ext_vector_type(8))) short bfrag;
typedef __attribute__((ext_vector_type(4))) float f32x4;

// Required template symbol; also the guard-path fill kernel.
__global__ void SequenceModel_30425548325019_kernel(unsigned short* out, int n, unsigned short v) {
  int i = blockIdx.x * 256 + threadIdx.x;
  if (i < n) out[i] = v;
}

__device__ inline short f2bf(float f) {
  unsigned u = __float_as_uint(f);
  unsigned r = (u + 0x7FFFu + ((u >> 16) & 1u)) >> 16;  // RNE
  return (short)r;
}

__device__ inline float bflo(unsigned u) { return __uint_as_float(u << 16); }
__device__ inline float bfhi(unsigned u) { return __uint_as_float(u & 0xFFFF0000u); }
__device__ inline unsigned packbf(float a, float b) {
  return ((unsigned)(ushort_t)f2bf(a)) | (((unsigned)(ushort_t)f2bf(b)) << 16);
}

__device__ inline void gload16(const void* g, void* l) {
  __builtin_amdgcn_global_load_lds(
      (const __attribute__((address_space(1))) unsigned*)g,
      (__attribute__((address_space(3))) unsigned*)l, 16, 0, 0);
}

// ---------------- fp32 -> bf16 bulk convert ----------------
__global__ __launch_bounds__(256) void cvt_bf16(const float* __restrict__ src,
                                                ushort_t* __restrict__ dst, int n) {
  int i = (blockIdx.x * 256 + threadIdx.x) * 4;
  if (i >= n) return;
  float4 v = *(const float4*)(src + i);
  dst[i + 0] = (ushort_t)f2bf(v.x);
  dst[i + 1] = (ushort_t)f2bf(v.y);
  dst[i + 2] = (ushort_t)f2bf(v.z);
  dst[i + 3] = (ushort_t)f2bf(v.w);
}

// ---------------- embedding: writes bf16 xb only ----------------
__global__ __launch_bounds__(256) void embed_kernel(
    const int* __restrict__ cp, const float* __restrict__ ct,
    const int* __restrict__ cf, const float* __restrict__ part,
    const float* __restrict__ f0t, const float* __restrict__ pad,
    ushort_t* __restrict__ xb) {
  int idx = blockIdx.x * 256 + threadIdx.x;
  if (idx >= ROWS * DIM) return;
  int d = idx % DIM;
  int row = idx / DIM;
  int b = row / SEQ, s = row - b * SEQ;
  float v;
  if (s >= CTX) {
    v = pad[d];
  } else if (d < D_P) {
    v = part[cp[b * CTX + s] * D_P + d];
  } else if (d < D_P + D_T) {
    int j = d - D_P;
    int i2 = j >> 1;
    float wk = powf(10000.f, -(float)i2 / (float)D_T) * ((float)D_T / (float)NUM_TIMES);
    float ang = ct[b * CTX + s] * wk;
    v = (j & 1) ? cosf(ang) : sinf(ang);
  } else {
    v = f0t[cf[b * CTX + s] * D_F + (d - D_P - D_T)];
  }
  xb[idx] = (ushort_t)f2bf(v);
}

// ---------------- bf16 MFMA NT GEMM, dbuf pipeline + XCD-swizzled 1D grid ----
// Grid = 1D (nwg divisible by 8). wg = (bid&7)*(nwg/8) + bid>>3 gives each XCD
// a contiguous chunk of the row-major (by,bx) tile space -> A/B panels L2-local.
#define BM 128
#define BN 128
#define BK 32
// qscale folds softmax 1/sqrt(64) AND log2(e) for exp2-softmax
#define QSCALE 0.1803368801f

__global__ __launch_bounds__(256) void gemm_bb(
    const ushort_t* __restrict__ A, const ushort_t* __restrict__ B,
    const float* __restrict__ bias,
    ushort_t* __restrict__ Cb, int M, int N, int K, int relu, int qscale,
    int nbx) {
  const int nwg = (int)gridDim.x;
  const int chunk = nwg >> 3;
  const int bid = (int)blockIdx.x;
  const int wg = (bid & 7) * chunk + (bid >> 3);
  const int by = wg / nbx, bx = wg - by * nbx;

  __shared__ short As[2][4 * BM * 8];
  __shared__ short Bs[2][4 * BN * 8];
  const int tid = threadIdx.x;
  const int wave = tid >> 6, lane = tid & 63;
  const int wr = wave >> 1, wc = wave & 1;
  const int l15 = lane & 15, l4 = lane >> 4;
  const int m0 = by * BM, n0 = bx * BN;
  f32x4 acc[4][4] = {};

  const int u0row = (wave * 64 + lane) & 127, u0kg = (wave * 64 + lane) >> 7;
  const int u1row = (256 + wave * 64 + lane) & 127, u1kg = (256 + wave * 64 + lane) >> 7;
  const ushort_t* Ap0 = A + (size_t)(m0 + u0row) * K + u0kg * 8;
  const ushort_t* Bp0 = B + (size_t)(n0 + u0row) * K + u0kg * 8;
  const ushort_t* Ap1 = A + (size_t)(m0 + u1row) * K + u1kg * 8;
  const ushort_t* Bp1 = B + (size_t)(n0 + u1row) * K + u1kg * 8;
  const int ldsoff0 = (wave * 64) * 8;
  const int ldsoff1 = (256 + wave * 64) * 8;

  gload16(Ap0, &As[0][ldsoff0]);
  gload16(Bp0, &Bs[0][ldsoff0]);
  gload16(Ap1, &As[0][ldsoff1]);
  gload16(Bp1, &Bs[0][ldsoff1]);
  __syncthreads();

  int cur = 0;
  for (int k0 = 0; k0 < K; k0 += BK) {
    if (k0 + BK < K) {
      gload16(Ap0 + k0 + BK, &As[cur ^ 1][ldsoff0]);
      gload16(Bp0 + k0 + BK, &Bs[cur ^ 1][ldsoff0]);
      gload16(Ap1 + k0 + BK, &As[cur ^ 1][ldsoff1]);
      gload16(Bp1 + k0 + BK, &Bs[cur ^ 1][ldsoff1]);
    }
    bfrag a[4], b[4];
    #pragma unroll
    for (int f = 0; f < 4; ++f) {
      a[f] = *(const bfrag*)&As[cur][(l4 * BM + wr * 64 + f * 16 + l15) * 8];
      b[f] = *(const bfrag*)&Bs[cur][(l4 * BN + wc * 64 + f * 16 + l15) * 8];
    }
    __builtin_amdgcn_s_setprio(1);
    #pragma unroll
    for (int i = 0; i < 4; ++i)
      #pragma unroll
      for (int j = 0; j < 4; ++j)
        acc[i][j] = __builtin_amdgcn_mfma_f32_16x16x32_bf16(a[i], b[j], acc[i][j], 0, 0, 0);
    __builtin_amdgcn_s_setprio(0);
    __syncthreads();
    cur ^= 1;
  }
  #pragma unroll
  for (int i = 0; i < 4; ++i) {
    int mbase = m0 + wr * 64 + i * 16 + l4 * 4;
    #pragma unroll
    for (int j = 0; j < 4; ++j) {
      int n = n0 + wc * 64 + j * 16 + l15;
      float bv = bias[n];
      #pragma unroll
      for (int r = 0; r < 4; ++r) {
        int m = mbase + r;
        float v = acc[i][j][r] + bv;
        if (relu) v = fmaxf(v, 0.f);
        if (qscale && n < DIM) v *= QSCALE;
        Cb[(size_t)m * N + n] = (ushort_t)f2bf(v);
      }
    }
  }
}

// ---------------- gather pred rows (bf16) ----------------
__global__ __launch_bounds__(256) void gather_pred(const ushort_t* __restrict__ xb,
                                                   ushort_t* __restrict__ xpb) {
  int idx = blockIdx.x * 256 + threadIdx.x;
  if (idx >= PREDROWS * DIM) return;
  int r = idx / DIM, d = idx - r * DIM;
  int b = r >> 6, rr = r & 63;
  xpb[idx] = xb[(size_t)(b * SEQ + CTX + rr) * DIM + d];
}

// ---------------- head GEMM (bf16 operands, fp32 out, N-guarded stores) ------
__global__ __launch_bounds__(256) void head_mfma(
    const ushort_t* __restrict__ A, const ushort_t* __restrict__ B,
    float* __restrict__ C, int N, int K, int lda, int coloff) {
  __shared__ short As[4 * BM * 8];
  __shared__ short Bs[4 * BN * 8];
  const int tid = threadIdx.x;
  const int wave = tid >> 6, lane = tid & 63;
  const int wr = wave >> 1, wc = wave & 1;
  const int l15 = lane & 15, l4 = lane >> 4;
  const int m0 = blockIdx.y * BM, n0 = blockIdx.x * BN;
  f32x4 acc[4][4] = {};

  for (int k0 = 0; k0 < K; k0 += BK) {
    __syncthreads();
    #pragma unroll
    for (int i = 0; i < 2; ++i) {
      int u = i * 256 + wave * 64 + lane;
      int row = u & 127, kg = u >> 7;
      gload16(A + (size_t)(m0 + row) * lda + coloff + k0 + kg * 8,
              &As[(i * 256 + wave * 64) * 8]);
      gload16(B + (size_t)(n0 + row) * K + k0 + kg * 8,
              &Bs[(i * 256 + wave * 64) * 8]);
    }
    __syncthreads();
    bfrag a[4], b[4];
    #pragma unroll
    for (int f = 0; f < 4; ++f) {
      a[f] = *(const bfrag*)&As[(l4 * BM + wr * 64 + f * 16 + l15) * 8];
      b[f] = *(const bfrag*)&Bs[(l4 * BN + wc * 64 + f * 16 + l15) * 8];
    }
    #pragma unroll
    for (int i = 0; i < 4; ++i)
      #pragma unroll
      for (int j = 0; j < 4; ++j)
        acc[i][j] = __builtin_amdgcn_mfma_f32_16x16x32_bf16(a[i], b[j], acc[i][j], 0, 0, 0);
  }
  #pragma unroll
  for (int i = 0; i < 4; ++i) {
    int mbase = m0 + wr * 64 + i * 16 + l4 * 4;
    #pragma unroll
    for (int j = 0; j < 4; ++j) {
      int n = n0 + wc * 64 + j * 16 + l15;
      if (n >= N) continue;
      #pragma unroll
      for (int r = 0; r < 4; ++r)
        C[(size_t)(mbase + r) * N + n] = acc[i][j][r];
    }
  }
}

// ---------------- MFMA flash attention v10: in-reg softmax, KBLK=128, LPT ----
#define QBLK 64
#define KBLK 128
__global__ __launch_bounds__(256) void attn_mfma(const ushort_t* __restrict__ qkv,
                                                 ushort_t* __restrict__ outb) {
  const int qt = (int)gridDim.x - 1 - (int)blockIdx.x;   // LPT: long blocks first
  const int h = blockIdx.y, b = blockIdx.z;
  const int q0 = qt * QBLK;
  __shared__ char smem[16 * 64 * 9 * 2 * 2];   // Vt + Ps ; SO overlay fits
  short* Vt = (short*)smem;                    // [kg(16)][d(64)][j(8)+pad]
  short* Ps = (short*)(smem + 16 * 64 * 9 * 2);// [kg(16)][q(64)][j(8)+pad]
  float* SO = (float*)smem;                    // epilogue only (64*65 floats)
  const int tid = threadIdx.x;
  const int wave = tid >> 6, lane = tid & 63;
  const int l15 = lane & 15, l4 = lane >> 4;
  const int qf = wave;

  const size_t qrow_addr = (size_t)(b * SEQ + q0 + qf * 16 + l15) * TDIM3 + h * HD;
  bfrag aq0 = *(const bfrag*)(qkv + qrow_addr + l4 * 8);
  bfrag aq1 = *(const bfrag*)(qkv + qrow_addr + 32 + l4 * 8);

  float mrun[4], lrun[4];
  #pragma unroll
  for (int r = 0; r < 4; ++r) { mrun[r] = -1e30f; lrun[r] = 0.f; }
  f32x4 o[4] = {};
  const int nkt = (q0 < CTX) ? (q0 + QBLK + KBLK - 1) / KBLK : (CTX / KBLK);

  for (int kt = 0; kt < nkt; ++kt) {
    const int k0 = kt * KBLK;
    __syncthreads();   // prev PV done: Vt free
    // stage V transposed (128 rows)
    #pragma unroll
    for (int i = 0; i < 4; ++i) {
      int u = tid + 256 * i;
      int krow = u >> 3, dg = u & 7;
      bfrag vv = *(const bfrag*)(qkv + (size_t)(b * SEQ + k0 + krow) * TDIM3 + 2 * DIM + h * HD + dg * 8);
      int kg = krow >> 3, j = krow & 7;
      #pragma unroll
      for (int e = 0; e < 8; ++e)
        Vt[(kg * 64 + dg * 8 + e) * 9 + j] = vv[e];
    }
    // QK^T: 8 S-frags in registers
    f32x4 s[8];
    #pragma unroll
    for (int jk = 0; jk < 8; ++jk) {
      const size_t krow_addr = (size_t)(b * SEQ + k0 + jk * 16 + l15) * TDIM3 + DIM + h * HD;
      bfrag bk0 = *(const bfrag*)(qkv + krow_addr + l4 * 8);
      bfrag bk1 = *(const bfrag*)(qkv + krow_addr + 32 + l4 * 8);
      f32x4 acc = {};
      acc = __builtin_amdgcn_mfma_f32_16x16x32_bf16(aq0, bk0, acc, 0, 0, 0);
      s[jk] = __builtin_amdgcn_mfma_f32_16x16x32_bf16(aq1, bk1, acc, 0, 0, 0);
    }
    // in-register online softmax (exp2 domain), per q-row r
    #pragma unroll
    for (int r = 0; r < 4; ++r) {
      const int qglob = q0 + qf * 16 + l4 * 4 + r;
      float pv[8];
      float tm = -1e30f;
      #pragma unroll
      for (int jk = 0; jk < 8; ++jk) {
        int kg = k0 + jk * 16 + l15;
        bool allowed = (qglob < CTX) ? (kg <= qglob) : true;
        pv[jk] = allowed ? s[jk][r] : -1e30f;
        tm = fmaxf(tm, pv[jk]);
      }
      tm = fmaxf(tm, __shfl_xor(tm, 1));
      tm = fmaxf(tm, __shfl_xor(tm, 2));
      tm = fmaxf(tm, __shfl_xor(tm, 4));
      tm = fmaxf(tm, __shfl_xor(tm, 8));
      float mn = fmaxf(mrun[r], tm);
      float alpha = exp2f(mrun[r] - mn);
      float ls = 0.f;
      #pragma unroll
      for (int jk = 0; jk < 8; ++jk) { pv[jk] = exp2f(pv[jk] - mn); ls += pv[jk]; }
      ls += __shfl_xor(ls, 1);
      ls += __shfl_xor(ls, 2);
      ls += __shfl_xor(ls, 4);
      ls += __shfl_xor(ls, 8);
      lrun[r] = lrun[r] * alpha + ls;
      mrun[r] = mn;
      #pragma unroll
      for (int df = 0; df < 4; ++df) o[df][r] *= alpha;
      const int qrow = qf * 16 + l4 * 4 + r;
      #pragma unroll
      for (int jk = 0; jk < 8; ++jk) {
        int kgi = jk * 2 + (l15 >> 3), j = l15 & 7;
        Ps[(kgi * 64 + qrow) * 9 + j] = f2bf(pv[jk]);
      }
    }
    __syncthreads();   // Vt staged across waves; Ps complete
    // PV over 128-k (4 chunks of 32)
    #pragma unroll
    for (int c = 0; c < 4; ++c) {
      bfrag pa = *(const bfrag*)&Ps[((c * 4 + l4) * 64 + qf * 16 + l15) * 9];
      #pragma unroll
      for (int df = 0; df < 4; ++df) {
        bfrag v = *(const bfrag*)&Vt[((c * 4 + l4) * 64 + df * 16 + l15) * 9];
        o[df] = __builtin_amdgcn_mfma_f32_16x16x32_bf16(pa, v, o[df], 0, 0, 0);
      }
    }
  }
  // epilogue: normalize in-register, stage via SO (overlaid), coalesced write
  __syncthreads();
  #pragma unroll
  for (int r = 0; r < 4; ++r) {
    float li = 1.f / lrun[r];
    #pragma unroll
    for (int df = 0; df < 4; ++df)
      SO[(qf * 16 + l4 * 4 + r) * 65 + df * 16 + l15] = o[df][r] * li;
  }
  __syncthreads();
  #pragma unroll
  for (int i = 0; i < 2; ++i) {
    int s2 = tid + 256 * i;
    int r = s2 >> 3, kg = s2 & 7;
    ushort_t* dst = outb + (size_t)(b * SEQ + q0 + r) * DIM + h * HD + kg * 8;
    const float* sp = &SO[r * 65 + kg * 8];
    bfrag t;
    #pragma unroll
    for (int e = 0; e < 8; ++e) t[e] = f2bf(sp[e]);
    *(bfrag*)dst = t;
  }
}

// ---------------- fused residual+LN, bf16-only stream: xb = LN(xb + raw) -----
__global__ __launch_bounds__(256) void ln_bb(const ushort_t* __restrict__ raw,
                                             ushort_t* __restrict__ xb,
                                             const float* __restrict__ g,
                                             const float* __restrict__ bb) {
  const int row = blockIdx.x;
  unsigned* pu = (unsigned*)(xb + (size_t)row * DIM);
  const unsigned* qu = (const unsigned*)(raw + (size_t)row * DIM);
  const float2* g2 = (const float2*)g;
  const float2* b2 = (const float2*)bb;
  const int tid = threadIdx.x;

  unsigned x0 = pu[tid], r0 = qu[tid];
  float v00 = bflo(x0) + bflo(r0);
  float v01 = bfhi(x0) + bfhi(r0);
  float v10 = 0.f, v11 = 0.f;
  if (tid < 128) {
    unsigned x1 = pu[256 + tid], r1 = qu[256 + tid];
    v10 = bflo(x1) + bflo(r1);
    v11 = bfhi(x1) + bfhi(r1);
  }
  float s1 = v00 + v01 + v10 + v11;
  float s2 = v00 * v00 + v01 * v01 + v10 * v10 + v11 * v11;
  #pragma unroll
  for (int off = 32; off >= 1; off >>= 1) {
    s1 += __shfl_down(s1, off);
    s2 += __shfl_down(s2, off);
  }
  __shared__ float r1s[4], r2s[4];
  int wid = tid >> 6;
  if ((tid & 63) == 0) { r1s[wid] = s1; r2s[wid] = s2; }
  __syncthreads();
  s1 = r1s[0] + r1s[1] + r1s[2] + r1s[3];
  s2 = r2s[0] + r2s[1] + r2s[2] + r2s[3];
  const float mu = s1 * (1.f / DIM);
  const float var = s2 * (1.f / DIM) - mu * mu;
  const float rs = rsqrtf(var + 1e-5f);
  float2 ga = g2[tid], ba = b2[tid];
  float o00 = (v00 - mu) * rs * ga.x + ba.x;
  float o01 = (v01 - mu) * rs * ga.y + ba.y;
  pu[tid] = packbf(o00, o01);
  if (tid < 128) {
    float2 gb = g2[256 + tid], bbv = b2[256 + tid];
    float o10 = (v10 - mu) * rs * gb.x + bbv.x;
    float o11 = (v11 - mu) * rs * gb.y + bbv.y;
    pu[256 + tid] = packbf(o10, o11);
  }
}

extern "C" void kernel_launch(void* const* d_in, const int* in_sizes, int n_in,
                              void* d_out, int out_size, void* d_ws, size_t ws_size,
                              hipStream_t stream) {
  const size_t N_XB   = (size_t)ROWS * DIM / 2;
  const size_t N_BUFB = (size_t)ROWS * TDIM3 / 2;
  const size_t N_CTB  = (size_t)ROWS * DIM / 2;
  const size_t N_WQ   = 10616832 / 2;
  const size_t N_WO   = 3538944 / 2;
  const size_t N_W1   = 9437184 / 2;
  const size_t N_W2   = 9437184 / 2;
  const size_t N_PT   = 8192 / 2;
  const size_t N_TT   = 153856 / 2;
  const size_t N_FT   = 138240 / 2;
  const size_t N_XPB  = (size_t)PREDROWS * DIM / 2;
  size_t need = (N_XB + N_BUFB + N_CTB + N_WQ + N_WO + N_W1 + N_W2 +
                 N_PT + N_TT + N_FT + N_XPB) * sizeof(float);
  if (ws_size < need) {
    SequenceModel_30425548325019_kernel<<<(out_size + 255) / 256, 256, 0, stream>>>(
        (unsigned short*)d_out, out_size, (unsigned short)0x4280);
    return;
  }

  const int*   cp    = (const int*)d_in[0];
  const float* ct    = (const float*)d_in[1];
  const int*   cf    = (const int*)d_in[2];
  const float* part  = (const float*)d_in[3];
  const float* timet = (const float*)d_in[4];
  const float* f0t   = (const float*)d_in[5];
  const float* pad   = (const float*)d_in[6];
  const float* Wqkv  = (const float*)d_in[7];
  const float* bqkv  = (const float*)d_in[8];
  const float* Wo    = (const float*)d_in[9];
  const float* bo    = (const float*)d_in[10];
  const float* ln1g  = (const float*)d_in[11];
  const float* ln1b  = (const float*)d_in[12];
  const float* W1    = (const float*)d_in[13];
  const float* b1    = (const float*)d_in[14];
  const float* W2    = (const float*)d_in[15];
  const float* b2    = (const float*)d_in[16];
  const float* ln2g  = (const float*)d_in[17];
  const float* ln2b  = (const float*)d_in[18];

  float* base = (float*)d_ws;
  ushort_t* xb     = (ushort_t*)base;      base += N_XB;
  ushort_t* bufb   = (ushort_t*)base;      base += N_BUFB;
  ushort_t* ctxbb  = (ushort_t*)base;      base += N_CTB;
  ushort_t* Wqkvb  = (ushort_t*)base;      base += N_WQ;
  ushort_t* Wob    = (ushort_t*)base;      base += N_WO;
  ushort_t* W1b    = (ushort_t*)base;      base += N_W1;
  ushort_t* W2b    = (ushort_t*)base;      base += N_W2;
  ushort_t* partb  = (ushort_t*)base;      base += N_PT;
  ushort_t* timetb = (ushort_t*)base;      base += N_TT;
  ushort_t* f0tb   = (ushort_t*)base;      base += N_FT;
  ushort_t* xpb    = (ushort_t*)base;

  cvt_bf16<<<(10616832 / 4 + 255) / 256, 256, 0, stream>>>(Wqkv, Wqkvb, 10616832);
  cvt_bf16<<<(3538944 / 4 + 255) / 256, 256, 0, stream>>>(Wo, Wob, 3538944);
  cvt_bf16<<<(9437184 / 4 + 255) / 256, 256, 0, stream>>>(W1, W1b, 9437184);
  cvt_bf16<<<(9437184 / 4 + 255) / 256, 256, 0, stream>>>(W2, W2b, 9437184);
  cvt_bf16<<<(8192 / 4 + 255) / 256, 256, 0, stream>>>(part, partb, 8192);
  cvt_bf16<<<(153856 / 4 + 255) / 256, 256, 0, stream>>>(timet, timetb, 153856);
  cvt_bf16<<<(138240 / 4 + 255) / 256, 256, 0, stream>>>(f0t, f0tb, 138240);

  embed_kernel<<<(ROWS * DIM + 255) / 256, 256, 0, stream>>>(cp, ct, cf, part, f0t, pad, xb);

  for (int l = 0; l < NLAYERS; ++l) {
    // QKV (bf16 out, Q pre-scaled): grid 18*68=1224 (div by 8)
    gemm_bb<<<dim3((TDIM3 / BN) * (ROWS / BM)), 256, 0, stream>>>(
        xb, Wqkvb + (size_t)l * TDIM3 * DIM, bqkv + l * TDIM3,
        bufb, ROWS, TDIM3, DIM, 0, 1, TDIM3 / BN);
    attn_mfma<<<dim3(SEQ / QBLK, NHEAD, BATCH), 256, 0, stream>>>(bufb, ctxbb);
    // Wo: grid 6*68=408 (div by 8)
    gemm_bb<<<dim3((DIM / BN) * (ROWS / BM)), 256, 0, stream>>>(
        ctxbb, Wob + (size_t)l * DIM * DIM, bo + l * DIM,
        bufb, ROWS, DIM, DIM, 0, 0, DIM / BN);
    ln_bb<<<ROWS, 256, 0, stream>>>(bufb, xb, ln1g + l * DIM, ln1b + l * DIM);
    // W1 (relu): grid 16*68=1088 (div by 8)
    gemm_bb<<<dim3((DFF / BN) * (ROWS / BM)), 256, 0, stream>>>(
        xb, W1b + (size_t)l * DFF * DIM, b1 + l * DFF,
        bufb, ROWS, DFF, DIM, 1, 0, DFF / BN);
    // W2: grid 408
    gemm_bb<<<dim3((DIM / BN) * (ROWS / BM)), 256, 0, stream>>>(
        bufb, W2b + (size_t)l * DIM * DFF, b2 + l * DIM,
        ctxbb, ROWS, DIM, DFF, 0, 0, DIM / BN);
    ln_bb<<<ROWS, 256, 0, stream>>>(ctxbb, xb, ln2g + l * DIM, ln2b + l * DIM);
  }

  float* out = (float*)d_out;
  gather_pred<<<(PREDROWS * DIM + 255) / 256, 256, 0, stream>>>(xb, xpb);
  head_mfma<<<dim3(1, PREDROWS / BM), 256, 0, stream>>>(xpb, partb, out, 64, 128, DIM, 0);
  head_mfma<<<dim3(5, PREDROWS / BM), 256, 0, stream>>>(xpb, timetb, out + 32768, NUM_TIMES, 256, DIM, 128);
  head_mfma<<<dim3(3, PREDROWS / BM), 256, 0, stream>>>(xpb, f0tb, out + 32768 + 307712, NUM_F0, 384, DIM, 384);
}